// Round 12
// baseline (2319.697 us; speedup 1.0000x reference)
//
#include <hip/hip_runtime.h>
#include <cstdint>

typedef __attribute__((ext_vector_type(8))) __bf16 bf16x8;
typedef __attribute__((ext_vector_type(4))) float f32x4;
typedef __attribute__((ext_vector_type(4))) unsigned int uint4v;
typedef __attribute__((ext_vector_type(2))) unsigned int uint2v;
typedef __attribute__((ext_vector_type(4))) float float4v;
typedef __attribute__((ext_vector_type(2))) long long2v;

__device__ __forceinline__ unsigned short f2bf(float x){
  union { float f; unsigned u; } v; v.f = x;
  unsigned r = v.u + 0x7FFFu + ((v.u >> 16) & 1u);
  return (unsigned short)(r >> 16);
}
__device__ __forceinline__ float bf2f(unsigned short h){
  union { unsigned u; float f; } v; v.u = ((unsigned)h) << 16;
  return v.f;
}
__device__ __forceinline__ float bflo(unsigned u){
  union { unsigned x; float f; } v; v.x = u << 16; return v.f;
}
__device__ __forceinline__ float bfhi(unsigned u){
  union { unsigned x; float f; } v; v.x = u & 0xFFFF0000u; return v.f;
}
__device__ __forceinline__ f32x4 MFMA16(bf16x8 a, bf16x8 b, f32x4 c){
  return __builtin_amdgcn_mfma_f32_16x16x32_bf16(a, b, c, 0, 0, 0);
}
__device__ __forceinline__ f32x4 MFMA8(long a, long b, f32x4 c){
  return __builtin_amdgcn_mfma_f32_16x16x32_fp8_fp8(a, b, c, 0, 0, 0);
}
__device__ __forceinline__ unsigned char f2fp8(float x){
  int p = __builtin_amdgcn_cvt_pk_fp8_f32(x, x, 0, false);
  return (unsigned char)(p & 0xFF);
}

// ---------------- prep ----------------
// wfrag8 (fp8 e4m3, value = fp8(16*W)): byte idx = (((w*4+kkp)*6+mg)*64 + l)*16 + ks*8 + e
//   kk = kkp*2+ks ; mg: 0=ihR 1=ihZ 2=ihN 3=hhR 4=hhZ 5=hhN
//   n = g*256 + w*16 + (l&15), k = kk*32 + (l>>4)*8 + e
// mlpfrag bf16: idx = w*512 + l*8 + e; n = w*16+(l&15), k = (l>>4)*8+e (k>=16 -> 0)
__global__ __launch_bounds__(256) void prep_k(
    const float* __restrict__ wih, const float* __restrict__ whh,
    const float* __restrict__ wl, const float* __restrict__ wr,
    const float* __restrict__ bl, const float* __restrict__ br,
    const float* __restrict__ fcw, const float* __restrict__ mlpw,
    const float* __restrict__ c2w, const float* __restrict__ c3w,
    unsigned char* __restrict__ wfrag8, unsigned short* __restrict__ mlpfrag,
    unsigned short* __restrict__ wlrT, unsigned short* __restrict__ fcwT,
    float* __restrict__ blbr,
    unsigned short* __restrict__ c2wb, unsigned short* __restrict__ c3wb){
  int i = blockIdx.x*256 + threadIdx.x;
  if (i < 393216){
    int b16 = i & 15;
    int l   = (i >> 4) & 63;
    int chunk = i >> 10;           // (w*4+kkp)*6+mg
    int wkp = chunk / 6;
    int mg  = chunk - 6*wkp;
    int w = wkp >> 2, kkp = wkp & 3;
    int ks = b16 >> 3, e = b16 & 7;
    int kk = kkp*2 + ks;
    int mat = mg / 3, g = mg - 3*(mg/3);
    int n = g*256 + w*16 + (l & 15);
    int k = kk*32 + (l >> 4)*8 + e;
    float v = 16.f * (mat ? whh[n*256 + k] : wih[n*256 + k]);
    wfrag8[i] = f2fp8(v);
    return;
  }
  i -= 393216;
  if (i < 8192){
    int w = i >> 9;
    int r4 = i & 511;
    int l = r4 >> 3, e = r4 & 7;
    int n = w*16 + (l & 15);
    int k = (l >> 4)*8 + e;
    mlpfrag[i] = (k < 16) ? f2bf(mlpw[k*256 + n]) : (unsigned short)0;
    return;
  }
  i -= 8192;
  if (i < 655360){
    int n = i >> 8, k = i & 255;
    float v = (n < 1280) ? wl[k*1280 + n] : wr[k*1280 + (n-1280)];
    wlrT[i] = f2bf(v); return;
  }
  i -= 655360;
  if (i < 802816){
    int n = i / 3136, k = i - n*3136;
    fcwT[i] = f2bf(fcw[k*256 + n]); return;
  }
  i -= 802816;
  if (i < 2560){
    blbr[i] = (i < 1280) ? bl[i] : br[i-1280];
    return;
  }
  i -= 2560;
  if (i < 32768){ c2wb[i] = f2bf(c2w[i]); return; }
  i -= 32768;
  if (i < 36864){ c3wb[i] = f2bf(c3w[i]); }
}

// ---------------- generic MFMA GEMM: C[m,n] = act(A[m,:]·B[n,:] + bias[n]) ----
__global__ __launch_bounds__(256) void gemm_k(const unsigned short* __restrict__ A,
              const unsigned short* __restrict__ B, const float* __restrict__ bias,
              unsigned short* __restrict__ C, int K, int ldc, int rowmul, int relu, int Nblk){
  __shared__ __align__(16) unsigned short As[64*32];
  __shared__ __align__(16) unsigned short Bs[64*32];
  int bid = blockIdx.x;
  int nb = bid % Nblk, mb = bid / Nblk;
  int t = threadIdx.x;
  int w = t >> 6, l = t & 63, lr = l & 15, lh = l >> 4;
  int sr = t >> 2, sq = t & 3;
  f32x4 acc[4];
  #pragma unroll
  for (int i=0;i<4;i++) acc[i] = (f32x4){0.f,0.f,0.f,0.f};
  int nkk = K >> 5;
  const size_t a_row = (size_t)(mb*64 + sr)*K;
  const size_t b_row = (size_t)(nb*64 + sr)*K;
  for (int kk=0;kk<nkk;kk++){
    uint4v av = *(const uint4v*)&A[a_row + kk*32 + sq*8];
    uint4v bv = *(const uint4v*)&B[b_row + kk*32 + sq*8];
    __syncthreads();
    *(uint4v*)((char*)As + ((sr*64 + sq*16) ^ ((sr&3)<<4))) = av;
    *(uint4v*)((char*)Bs + ((sr*64 + sq*16) ^ ((sr&3)<<4))) = bv;
    __syncthreads();
    int brow = w*16 + lr;
    bf16x8 bfr = *(const bf16x8*)((char*)Bs + ((brow*64 + lh*16) ^ ((brow&3)<<4)));
    #pragma unroll
    for (int mt=0;mt<4;mt++){
      int arow = mt*16 + lr;
      bf16x8 afr = *(const bf16x8*)((char*)As + ((arow*64 + lh*16) ^ ((arow&3)<<4)));
      acc[mt] = MFMA16(afr, bfr, acc[mt]);
    }
  }
  int col = nb*64 + w*16 + lr;
  float bn = bias[col];
  #pragma unroll
  for (int mt=0;mt<4;mt++){
    #pragma unroll
    for (int r=0;r<4;r++){
      int row = mb*64 + mt*16 + lh*4 + r;
      float v = acc[mt][r] + bn;
      if (relu) v = fmaxf(v, 0.f);
      C[(size_t)row*rowmul*ldc + col] = f2bf(v);
    }
  }
}

// ---------------- FC split-K GEMM: 112 blocks = 16 tiles x 7 K-slices, f32 partials ----
__global__ __launch_bounds__(256) void gemm_fc_k(const unsigned short* __restrict__ A,
              const unsigned short* __restrict__ B, float* __restrict__ P){
  __shared__ __align__(16) unsigned short As[64*32];
  __shared__ __align__(16) unsigned short Bs[64*32];
  int bid = blockIdx.x;
  int s = bid % 7, tile = bid / 7;
  int nb = tile & 3, mb = tile >> 2;
  int t = threadIdx.x;
  int w = t >> 6, l = t & 63, lr = l & 15, lh = l >> 4;
  int sr = t >> 2, sq = t & 3;
  f32x4 acc[4];
  #pragma unroll
  for (int i=0;i<4;i++) acc[i] = (f32x4){0.f,0.f,0.f,0.f};
  const int K = 3136;
  const size_t a_row = (size_t)(mb*64 + sr)*K;
  const size_t b_row = (size_t)(nb*64 + sr)*K;
  for (int kk = s*14; kk < s*14 + 14; kk++){
    uint4v av = *(const uint4v*)&A[a_row + kk*32 + sq*8];
    uint4v bv = *(const uint4v*)&B[b_row + kk*32 + sq*8];
    __syncthreads();
    *(uint4v*)((char*)As + ((sr*64 + sq*16) ^ ((sr&3)<<4))) = av;
    *(uint4v*)((char*)Bs + ((sr*64 + sq*16) ^ ((sr&3)<<4))) = bv;
    __syncthreads();
    int brow = w*16 + lr;
    bf16x8 bfr = *(const bf16x8*)((char*)Bs + ((brow*64 + lh*16) ^ ((brow&3)<<4)));
    #pragma unroll
    for (int mt=0;mt<4;mt++){
      int arow = mt*16 + lr;
      bf16x8 afr = *(const bf16x8*)((char*)As + ((arow*64 + lh*16) ^ ((arow&3)<<4)));
      acc[mt] = MFMA16(afr, bfr, acc[mt]);
    }
  }
  int col = nb*64 + w*16 + lr;
  #pragma unroll
  for (int mt=0;mt<4;mt++){
    #pragma unroll
    for (int r=0;r<4;r++){
      int row = mb*64 + mt*16 + lh*4 + r;
      P[(size_t)s*65536 + row*256 + col] = acc[mt][r];
    }
  }
}

// ---------------- FC reduce: sum 7 partials + bias + relu -> nemb node-0 rows ----
__global__ __launch_bounds__(256) void fc_red_k(const float* __restrict__ P,
              const float* __restrict__ fcb, unsigned short* __restrict__ nemb){
  int idx = blockIdx.x*256 + threadIdx.x;       // 65536 total
  int row = idx >> 8, col = idx & 255;
  float sum = fcb[col];
  #pragma unroll
  for (int k=0;k<7;k++) sum += P[k*65536 + idx];
  nemb[(size_t)row*25*256 + col] = f2bf(fmaxf(sum, 0.f));
}

// ---------------- mega kernel: blocks 0..191 = GRU (R9); 192..255 = full CNN chain ------
// GRU: 16 waves, block owns 32 rows, wave owns 16 h-cols; fp8 weights/acts, f32 reg h.
// CNN: block cb=blk-192 handles batches {cb, cb+64, cb+128, cb+192}: conv1->conv2->conv3
//      entirely in LDS; only conv3 output goes to global (c3o for the FC GEMM).
__global__ __launch_bounds__(1024, 4)
void gruconv_k(const float* __restrict__ obs,
              const unsigned char* __restrict__ wfrag8,
              const unsigned short* __restrict__ mlpfrag,
              const float* __restrict__ mlpb,
              const float* __restrict__ bih, const float* __restrict__ bhh,
              unsigned short* __restrict__ nemb,
              const float* __restrict__ cin, const float* __restrict__ c1w,
              const float* __restrict__ c1b,
              const unsigned short* __restrict__ c2wb, const float* __restrict__ c2b,
              const unsigned short* __restrict__ c3wb, const float* __restrict__ c3b,
              unsigned short* __restrict__ c3o){
  __shared__ __align__(16) char smem[135040];

  const int t = threadIdx.x, blk = blockIdx.x;

  if (blk >= 192){
    // ================= CNN chain path =================
    float* img = (float*)smem;                          // 84672 B [3][84][84]
    float* w1  = (float*)(smem + 84672);                // 24576 B [32][3][8][8]
    float* b1  = (float*)(smem + 109248);               // 128 B
    unsigned short* c1s = (unsigned short*)(smem + 109376); // 25600 B [32][20][20]
    unsigned short* w2s = (unsigned short*)smem;        // 65536 B (phase2 overlay)
    float* b2  = (float*)(smem + 65536);                // 256 B
    unsigned short* c2s = (unsigned short*)(smem + 76160);  // 10368 B [64][9][9]
    unsigned short* w3s = (unsigned short*)smem;        // 73728 B (phase3 overlay)
    float* b3  = (float*)(smem + 73728);                // 256 B
    int cb = blk - 192;
    for (int idx = t; idx < 6144; idx += 1024) w1[idx] = c1w[idx];
    if (t < 32) b1[t] = c1b[t];
    for (int i=0;i<4;i++){
      int b = cb + (i<<6);
      __syncthreads();                  // previous iter's w3s/c2s reads done before img overlay
      for (int idx = t; idx < 21168; idx += 1024) img[idx] = cin[(size_t)b*21168 + idx];
      __syncthreads();
      // conv1: [3,84,84] -> [32,20,20], k=8 s=4, relu
      for (int p = t; p < 12800; p += 1024){
        int oc = p / 400; int rem = p - oc*400;
        int oy = rem / 20, ox = rem - (rem/20)*20;
        float a = b1[oc];
        #pragma unroll
        for (int ic=0;ic<3;ic++){
          #pragma unroll
          for (int ky=0;ky<8;ky++){
            const float* row = &img[(ic*84 + oy*4+ky)*84 + ox*4];
            const float* wp = &w1[(oc*3 + ic)*64 + ky*8];
            #pragma unroll
            for (int kx=0;kx<8;kx++) a += row[kx]*wp[kx];
          }
        }
        c1s[p] = f2bf(fmaxf(a, 0.f));
      }
      __syncthreads();                  // conv1 done; img region now dead
      for (int idx = t; idx < 32768; idx += 1024) w2s[idx] = c2wb[idx];
      if (t < 64) b2[t] = c2b[t];
      __syncthreads();
      // conv2: [32,20,20] -> [64,9,9], k=4 s=2, relu
      for (int p = t; p < 5184; p += 1024){
        int oc = p / 81; int rem = p - oc*81;
        int oy = rem / 9, ox = rem - (rem/9)*9;
        float a = b2[oc];
        #pragma unroll 4
        for (int ic=0;ic<32;ic++){
          #pragma unroll
          for (int ky=0;ky<4;ky++){
            const unsigned short* row = &c1s[(ic*20 + oy*2+ky)*20 + ox*2];
            const unsigned short* wp = &w2s[((oc*32+ic)*4+ky)*4];
            #pragma unroll
            for (int kx=0;kx<4;kx++) a += bf2f(row[kx])*bf2f(wp[kx]);
          }
        }
        c2s[p] = f2bf(fmaxf(a, 0.f));
      }
      __syncthreads();                  // conv2 done; w2s region dead
      for (int idx = t; idx < 36864; idx += 1024) w3s[idx] = c3wb[idx];
      if (t < 64) b3[t] = c3b[t];
      __syncthreads();
      // conv3: [64,9,9] -> [64,7,7] flat 3136, k=3 s=1, relu -> global
      for (int p = t; p < 3136; p += 1024){
        int oc = p / 49; int rem = p - oc*49;
        int oy = rem / 7, ox = rem - (rem/7)*7;
        float a = b3[oc];
        for (int ic=0;ic<64;ic++){
          #pragma unroll
          for (int ky=0;ky<3;ky++){
            const unsigned short* row = &c2s[(ic*9 + oy+ky)*9 + ox];
            const unsigned short* wp = &w3s[((oc*64+ic)*3+ky)*3];
            #pragma unroll
            for (int kx=0;kx<3;kx++) a += bf2f(row[kx])*bf2f(wp[kx]);
          }
        }
        c3o[(size_t)b*3136 + p] = f2bf(fmaxf(a, 0.f));
      }
    }
    return;
  }

  // ================= GRU path (exact R9) =================
  unsigned short* obsA = (unsigned short*)smem;           // bf16 [32][32], swz ^((row&3)<<4)
  unsigned char* e8_0 = (unsigned char*)(smem + 2048);    // fp8 [32][256], swz ^((m&15)<<3)
  unsigned char* e8_1 = (unsigned char*)(smem + 10240);
  unsigned char* h8   = (unsigned char*)(smem + 18432);

  obsA[t & 1023] = 0;                       // zero incl. k>=16 pad (stays zero)
  for (int j = t; j < 8192; j += 1024) h8[j] = 0;

  const int w = t >> 6, l = t & 63, lr = l & 15, lh = l >> 4;
  const int jcol = w*16 + lr;
  const float bR  = bih[jcol]     + bhh[jcol];
  const float bZ  = bih[256+jcol] + bhh[256+jcol];
  const float bXN = bih[512+jcol];
  const float bHN = bhh[512+jcol];
  const float bMb = mlpb[jcol];
  const bf16x8 bMLP = *(const bf16x8*)(mlpfrag + w*512 + l*8);

  const unsigned char* wb8 = wfrag8 + w*24576 + l*16;

  // obs stage: 128 threads, float4 each. row = t>>2, k4 = t&3
  const int srow = t >> 2, sk4 = t & 3;
  int rrS = blk*32 + srow; int bS = rrS/24, ndS = 1 + (rrS - bS*24);
  const float* obase4 = obs + (size_t)(bS*25 + ndS)*800 + sk4*4;
  const int obyte = (srow*64 + sk4*8) ^ ((srow&3)<<4);

  const int a8off = lr*256 + lh*8;   // fp8 A-frag base (row=lr)
  const int xr8 = lr << 3;           // full-row swizzle (row&15 == lr for both m-tiles)
  const int o16 = lh*16;
  const int oa0b = (lr*64 + o16) ^ ((lr&3)<<4);
  const int oa1b = ((16+lr)*64 + o16) ^ ((lr&3)<<4);
  const int hw0 = jcol;              // h8/e8 write col
  const float S = 1.f/256.f;

  f32x4 hs0 = (f32x4){0.f,0.f,0.f,0.f};   // h state rows lh*4+r, col jcol
  f32x4 hs1 = (f32x4){0.f,0.f,0.f,0.f};   // rows 16+lh*4+r

#define EMB_COMPUTE(DST) { \
  f32x4 e0 = (f32x4){0.f,0.f,0.f,0.f}, e1 = (f32x4){0.f,0.f,0.f,0.f}; \
  bf16x8 oa0 = *(const bf16x8*)((char*)obsA + oa0b); \
  bf16x8 oa1 = *(const bf16x8*)((char*)obsA + oa1b); \
  e0 = MFMA16(oa0, bMLP, e0); \
  e1 = MFMA16(oa1, bMLP, e1); \
  _Pragma("unroll") \
  for (int r=0;r<4;r++){ \
    int m = lh*4 + r; \
    (DST)[(m*256 + hw0) ^ ((m&15)<<3)] = f2fp8(fmaxf(e0[r] + bMb, 0.f)*16.f); \
    int m2 = m + 16; \
    (DST)[(m2*256 + hw0) ^ ((m2&15)<<3)] = f2fp8(fmaxf(e1[r] + bMb, 0.f)*16.f); \
  } }

  // ---- prologue: stage obs(0), emb(0) -> e8_0 ----
  __syncthreads();
  if (t < 128){
    float4v ov = *(const float4v*)(obase4);
    uint2v pk;
    pk[0] = (unsigned)f2bf(ov[0]) | ((unsigned)f2bf(ov[1]) << 16);
    pk[1] = (unsigned)f2bf(ov[2]) | ((unsigned)f2bf(ov[3]) << 16);
    *(uint2v*)((char*)obsA + obyte) = pk;
  }
  __syncthreads();
  EMB_COMPUTE(e8_0)
  __syncthreads();

  for (int step=0; step<50; step++){
    const unsigned char* ebuf = (step & 1) ? e8_1 : e8_0;
    unsigned char* nbuf = (step & 1) ? e8_0 : e8_1;
    const bool stg = (t < 128) && (step < 49);
    // ---- phase 1: issue obs(t+1) loads, main fp8 GEMM(t), write obsA ----
    float4v ov;
    if (stg) ov = *(const float4v*)(obase4 + (size_t)(step+1)*16);

    f32x4 aR0=(f32x4){0,0,0,0}, aR1=(f32x4){0,0,0,0};
    f32x4 aZ0=(f32x4){0,0,0,0}, aZ1=(f32x4){0,0,0,0};
    f32x4 aN0=(f32x4){0,0,0,0}, aN1=(f32x4){0,0,0,0};   // xn part
    f32x4 aM0=(f32x4){0,0,0,0}, aM1=(f32x4){0,0,0,0};   // hn part
    __builtin_amdgcn_s_setprio(1);
    #pragma unroll 2
    for (int kkp=0;kkp<4;kkp++){
      const unsigned char* wk8 = wb8 + kkp*6144;
      long2v wIR = *(const long2v*)(wk8);
      long2v wIZ = *(const long2v*)(wk8 + 1024);
      long2v wIN = *(const long2v*)(wk8 + 2048);
      long2v wHR = *(const long2v*)(wk8 + 3072);
      long2v wHZ = *(const long2v*)(wk8 + 4096);
      long2v wHN = *(const long2v*)(wk8 + 5120);
      {
        int kk = kkp*2;
        int ab = a8off + kk*32;
        long eA0 = *(const long*)(ebuf + (ab ^ xr8));
        long eA1 = *(const long*)(ebuf + ((ab + 4096) ^ xr8));
        long hA0 = *(const long*)(h8 + (ab ^ xr8));
        long hA1 = *(const long*)(h8 + ((ab + 4096) ^ xr8));
        aR0 = MFMA8(eA0, wIR[0], aR0);  aR0 = MFMA8(hA0, wHR[0], aR0);
        aR1 = MFMA8(eA1, wIR[0], aR1);  aR1 = MFMA8(hA1, wHR[0], aR1);
        aZ0 = MFMA8(eA0, wIZ[0], aZ0);  aZ0 = MFMA8(hA0, wHZ[0], aZ0);
        aZ1 = MFMA8(eA1, wIZ[0], aZ1);  aZ1 = MFMA8(hA1, wHZ[0], aZ1);
        aN0 = MFMA8(eA0, wIN[0], aN0);  aN1 = MFMA8(eA1, wIN[0], aN1);
        aM0 = MFMA8(hA0, wHN[0], aM0);  aM1 = MFMA8(hA1, wHN[0], aM1);
      }
      {
        int kk = kkp*2 + 1;
        int ab = a8off + kk*32;
        long eA0 = *(const long*)(ebuf + (ab ^ xr8));
        long eA1 = *(const long*)(ebuf + ((ab + 4096) ^ xr8));
        long hA0 = *(const long*)(h8 + (ab ^ xr8));
        long hA1 = *(const long*)(h8 + ((ab + 4096) ^ xr8));
        aR0 = MFMA8(eA0, wIR[1], aR0);  aR0 = MFMA8(hA0, wHR[1], aR0);
        aR1 = MFMA8(eA1, wIR[1], aR1);  aR1 = MFMA8(hA1, wHR[1], aR1);
        aZ0 = MFMA8(eA0, wIZ[1], aZ0);  aZ0 = MFMA8(hA0, wHZ[1], aZ0);
        aZ1 = MFMA8(eA1, wIZ[1], aZ1);  aZ1 = MFMA8(hA1, wHZ[1], aZ1);
        aN0 = MFMA8(eA0, wIN[1], aN0);  aN1 = MFMA8(eA1, wIN[1], aN1);
        aM0 = MFMA8(hA0, wHN[1], aM0);  aM1 = MFMA8(hA1, wHN[1], aM1);
      }
    }
    __builtin_amdgcn_s_setprio(0);
    if (stg){
      uint2v pk;
      pk[0] = (unsigned)f2bf(ov[0]) | ((unsigned)f2bf(ov[1]) << 16);
      pk[1] = (unsigned)f2bf(ov[2]) | ((unsigned)f2bf(ov[3]) << 16);
      *(uint2v*)((char*)obsA + obyte) = pk;
    }
    __syncthreads();   // GEMM LDS reads done; obsA(t+1) visible
    // ---- phase 2: emb(t+1) (MFMA) + gate update (VALU, h in f32 regs) ----
    if (step < 49){
      EMB_COMPUTE(nbuf)
    }
    #pragma unroll
    for (int mt=0;mt<2;mt++){
      f32x4 vR = mt ? aR1 : aR0;
      f32x4 vZ = mt ? aZ1 : aZ0;
      f32x4 vN = mt ? aN1 : aN0;
      f32x4 vM = mt ? aM1 : aM0;
      #pragma unroll
      for (int r=0;r<4;r++){
        float rp = vR[r]*S + bR;
        float zp = vZ[r]*S + bZ;
        float xn = vN[r]*S + bXN;
        float hn = vM[r]*S + bHN;
        float rg = 1.f/(1.f + __expf(-rp));
        float zg = 1.f/(1.f + __expf(-zp));
        float arg = xn + rg*hn;
        float e2 = __expf(2.f*arg);
        float nv = (e2 - 1.f)/(e2 + 1.f);
        float hold = mt ? hs1[r] : hs0[r];
        float hnew = (1.f - zg)*nv + zg*hold;
        if (mt) hs1[r] = hnew; else hs0[r] = hnew;
        int m = mt*16 + lh*4 + r;
        h8[(m*256 + hw0) ^ ((m&15)<<3)] = f2fp8(hnew*16.f);
        if (step == 49){
          int rr = blk*32 + m; int b = rr/24; int nd = 1 + (rr - b*24);
          nemb[(size_t)(b*25+nd)*256 + jcol] = f2bf(hnew);
        }
      }
    }
    __syncthreads();   // h8(t) + e8(t+1) visible for next main GEMM
  }
#undef EMB_COMPUTE
}

// ---------------- GAT scores + softmax + node0 out + dueling head ----------------
__global__ __launch_bounds__(256) void gat_k(const int* __restrict__ edges,
              const unsigned short* __restrict__ glgr,
              const float* __restrict__ att, const float* __restrict__ gbias,
              const float* __restrict__ hidw, const float* __restrict__ hidb,
              const float* __restrict__ outw, const float* __restrict__ outb,
              const float* __restrict__ advw, const float* __restrict__ advb,
              float* __restrict__ out){
  __shared__ int src_s[125], dst_s[125];
  __shared__ __align__(16) float att_s[1280];
  __shared__ float sc[125][5], al[125][5];
  __shared__ float mx[25][5], dn[25][5];
  __shared__ float g0[256], hh[256];
  __shared__ float adv_s[8], v_s;
  __shared__ int e0[125]; __shared__ int ne0;

  int b = blockIdx.x, t = threadIdx.x;
  if (t < 100){ src_s[t] = edges[b*200 + t]; dst_s[t] = edges[b*200 + 100 + t]; }
  else if (t < 125){ src_s[t] = t - 100; dst_s[t] = t - 100; }
  for (int j = t; j < 1280; j += 256) att_s[j] = att[j];
  __syncthreads();
  if (t == 0){ int c = 0; for (int e=0;e<125;e++) if (dst_s[e]==0) e0[c++]=e; ne0 = c; }
  const unsigned short* gbase = glgr + (size_t)b*25*2560;
  for (int p = t; p < 625; p += 256){
    int e = p/5, h = p - 5*(p/5);
    const unsigned short* glp = gbase + src_s[e]*2560 + h*256;
    const unsigned short* grp = gbase + dst_s[e]*2560 + 1280 + h*256;
    const float* ap = &att_s[h*256];
    float acc = 0.f;
    #pragma unroll 4
    for (int c=0;c<256;c+=8){
      uint4v gu = *(const uint4v*)&glp[c];
      uint4v ru = *(const uint4v*)&grp[c];
      #pragma unroll
      for (int q=0;q<4;q++){
        float s0 = bflo(gu[q]) + bflo(ru[q]);
        float s1 = bfhi(gu[q]) + bfhi(ru[q]);
        s0 = (s0 > 0.f) ? s0 : 0.2f*s0;
        s1 = (s1 > 0.f) ? s1 : 0.2f*s1;
        acc += s0*ap[c+2*q] + s1*ap[c+2*q+1];
      }
    }
    sc[e][h] = acc;
  }
  __syncthreads();
  if (t < 125){
    int j = t/5, h = t - 5*(t/5);
    float m = -1e30f;
    for (int e=0;e<125;e++) if (dst_s[e]==j) m = fmaxf(m, sc[e][h]);
    float d = 0.f;
    for (int e=0;e<125;e++) if (dst_s[e]==j) d += __expf(sc[e][h]-m);
    mx[j][h] = m; dn[j][h] = d;
  }
  __syncthreads();
  for (int p = t; p < 625; p += 256){
    int e = p/5, h = p - 5*(p/5);
    int dd = dst_s[e];
    al[e][h] = __expf(sc[e][h] - mx[dd][h]) / dn[dd][h];
  }
  __syncthreads();
  if (t < 101){
    out[2048 + b*101 + t] = (al[t][0]+al[t][1]+al[t][2]+al[t][3]+al[t][4])*0.2f;
  }
  {
    float acc = 0.f;
    for (int x=0;x<ne0;x++){
      int e = e0[x]; int s = src_s[e];
      const unsigned short* glp = gbase + s*2560 + t;
      #pragma unroll
      for (int h=0;h<5;h++) acc += al[e][h]*bf2f(glp[h*256]);
    }
    g0[t] = acc*0.2f + gbias[t];
  }
  __syncthreads();
  {
    float acc = hidb[t];
    for (int k=0;k<256;k++) acc += g0[k]*hidw[k*256+t];
    hh[t] = fmaxf(acc, 0.f);
  }
  __syncthreads();
  if (t < 8){
    float acc = advb[t];
    for (int k=0;k<256;k++) acc += hh[k]*advw[k*8+t];
    adv_s[t] = acc;
  } else if (t == 8){
    float acc = outb[0];
    for (int k=0;k<256;k++) acc += hh[k]*outw[k];
    v_s = acc;
  }
  __syncthreads();
  if (t < 8){
    float m = adv_s[0]+adv_s[1]+adv_s[2]+adv_s[3]+adv_s[4]+adv_s[5]+adv_s[6]+adv_s[7];
    out[b*8+t] = v_s + adv_s[t] - m*0.125f;
  }
}

extern "C" void kernel_launch(void* const* d_in, const int* in_sizes, int n_in,
                              void* d_out, int out_size, void* d_ws, size_t ws_size,
                              hipStream_t stream){
  const float* obs     = (const float*)d_in[0];
  const float* obs_map = (const float*)d_in[1];
  const int*   edges   = (const int*)d_in[2];
  const float* mlp_w = (const float*)d_in[4];
  const float* mlp_b = (const float*)d_in[5];
  const float* c1w = (const float*)d_in[6];  const float* c1b = (const float*)d_in[7];
  const float* c2w = (const float*)d_in[8];  const float* c2b = (const float*)d_in[9];
  const float* c3w = (const float*)d_in[10]; const float* c3b = (const float*)d_in[11];
  const float* fcw = (const float*)d_in[12]; const float* fcb = (const float*)d_in[13];
  const float* wih = (const float*)d_in[14]; const float* whh = (const float*)d_in[15];
  const float* bih = (const float*)d_in[16]; const float* bhh = (const float*)d_in[17];
  const float* gwl = (const float*)d_in[18]; const float* gbl = (const float*)d_in[19];
  const float* gwr = (const float*)d_in[20]; const float* gbr = (const float*)d_in[21];
  const float* gatt = (const float*)d_in[22]; const float* gbias = (const float*)d_in[23];
  const float* hidw = (const float*)d_in[24]; const float* hidb = (const float*)d_in[25];
  const float* outw = (const float*)d_in[26]; const float* outb = (const float*)d_in[27];
  const float* advw = (const float*)d_in[28]; const float* advb = (const float*)d_in[29];
  float* out = (float*)d_out;
  char* ws = (char*)d_ws;

  // workspace layout (c3o + fcpart aliased under glgr; consumed before glgr write)
  unsigned short* c3o  = (unsigned short*)(ws + 0);          // 1,605,632 B
  float*          fcpart = (float*)(ws + 16000000);          // 1,835,008 B (inside glgr window)
  unsigned short* glgr = (unsigned short*)(ws + 0);          // 32,768,000 B
  size_t o = 32768000;
  unsigned short* nemb    = (unsigned short*)(ws + o); o += 3276800;
  unsigned char*  wfrag8  = (unsigned char*)(ws + o);  o += 393216;
  unsigned short* mlpfrag = (unsigned short*)(ws + o); o += 16384;
  unsigned short* wlrT    = (unsigned short*)(ws + o); o += 1310720;
  unsigned short* fcwT    = (unsigned short*)(ws + o); o += 1605632;
  float* blbr             = (float*)(ws + o); o += 10240;
  unsigned short* c2wb    = (unsigned short*)(ws + o); o += 65536;
  unsigned short* c3wb    = (unsigned short*)(ws + o); o += 73728;

  prep_k<<<7546, 256, 0, stream>>>(wih, whh, gwl, gwr, gbl, gbr, fcw, mlp_w, c2w, c3w,
                                   wfrag8, mlpfrag, wlrT, fcwT, blbr, c2wb, c3wb);
  gruconv_k<<<256, 1024, 0, stream>>>(obs, wfrag8, mlpfrag, mlp_b, bih, bhh, nemb,
                                      obs_map, c1w, c1b, c2wb, c2b, c3wb, c3b, c3o);
  gemm_fc_k<<<112, 256, 0, stream>>>(c3o, fcwT, fcpart);                          // FC split-K
  fc_red_k<<<256, 256, 0, stream>>>(fcpart, fcb, nemb);                           // -> node 0
  gemm_k<<<4000, 256, 0, stream>>>(nemb, wlrT, blbr, glgr, 256, 2560, 1, 0, 40);  // gl|gr
  gat_k<<<256, 256, 0, stream>>>(edges, glgr, gatt, gbias, hidw, hidb, outw, outb, advw, advb, out);
}

// Round 13
// 1334.126 us; speedup vs baseline: 1.7387x; 1.7387x over previous
//
#include <hip/hip_runtime.h>
#include <cstdint>

typedef __attribute__((ext_vector_type(8))) __bf16 bf16x8;
typedef __attribute__((ext_vector_type(4))) float f32x4;
typedef __attribute__((ext_vector_type(4))) unsigned int uint4v;
typedef __attribute__((ext_vector_type(2))) unsigned int uint2v;
typedef __attribute__((ext_vector_type(4))) float float4v;
typedef __attribute__((ext_vector_type(2))) long long2v;

__device__ __forceinline__ unsigned short f2bf(float x){
  union { float f; unsigned u; } v; v.f = x;
  unsigned r = v.u + 0x7FFFu + ((v.u >> 16) & 1u);
  return (unsigned short)(r >> 16);
}
__device__ __forceinline__ float bf2f(unsigned short h){
  union { unsigned u; float f; } v; v.u = ((unsigned)h) << 16;
  return v.f;
}
__device__ __forceinline__ float bflo(unsigned u){
  union { unsigned x; float f; } v; v.x = u << 16; return v.f;
}
__device__ __forceinline__ float bfhi(unsigned u){
  union { unsigned x; float f; } v; v.x = u & 0xFFFF0000u; return v.f;
}
__device__ __forceinline__ f32x4 MFMA16(bf16x8 a, bf16x8 b, f32x4 c){
  return __builtin_amdgcn_mfma_f32_16x16x32_bf16(a, b, c, 0, 0, 0);
}
__device__ __forceinline__ f32x4 MFMA8(long a, long b, f32x4 c){
  return __builtin_amdgcn_mfma_f32_16x16x32_fp8_fp8(a, b, c, 0, 0, 0);
}
__device__ __forceinline__ unsigned char f2fp8(float x){
  int p = __builtin_amdgcn_cvt_pk_fp8_f32(x, x, 0, false);
  return (unsigned char)(p & 0xFF);
}

// ---------------- prep ----------------
__global__ __launch_bounds__(256) void prep_k(
    const float* __restrict__ wih, const float* __restrict__ whh,
    const float* __restrict__ wl, const float* __restrict__ wr,
    const float* __restrict__ bl, const float* __restrict__ br,
    const float* __restrict__ fcw, const float* __restrict__ mlpw,
    const float* __restrict__ c2w, const float* __restrict__ c3w,
    unsigned char* __restrict__ wfrag8, unsigned short* __restrict__ mlpfrag,
    unsigned short* __restrict__ wlrT, unsigned short* __restrict__ fcwT,
    float* __restrict__ blbr,
    unsigned short* __restrict__ c2wb, unsigned short* __restrict__ c3wb){
  int i = blockIdx.x*256 + threadIdx.x;
  if (i < 393216){
    int b16 = i & 15;
    int l   = (i >> 4) & 63;
    int chunk = i >> 10;           // (w*4+kkp)*6+mg
    int wkp = chunk / 6;
    int mg  = chunk - 6*wkp;
    int w = wkp >> 2, kkp = wkp & 3;
    int ks = b16 >> 3, e = b16 & 7;
    int kk = kkp*2 + ks;
    int mat = mg / 3, g = mg - 3*(mg/3);
    int n = g*256 + w*16 + (l & 15);
    int k = kk*32 + (l >> 4)*8 + e;
    float v = 16.f * (mat ? whh[n*256 + k] : wih[n*256 + k]);
    wfrag8[i] = f2fp8(v);
    return;
  }
  i -= 393216;
  if (i < 8192){
    int w = i >> 9;
    int r4 = i & 511;
    int l = r4 >> 3, e = r4 & 7;
    int n = w*16 + (l & 15);
    int k = (l >> 4)*8 + e;
    mlpfrag[i] = (k < 16) ? f2bf(mlpw[k*256 + n]) : (unsigned short)0;
    return;
  }
  i -= 8192;
  if (i < 655360){
    int n = i >> 8, k = i & 255;
    float v = (n < 1280) ? wl[k*1280 + n] : wr[k*1280 + (n-1280)];
    wlrT[i] = f2bf(v); return;
  }
  i -= 655360;
  if (i < 802816){
    int n = i / 3136, k = i - n*3136;
    fcwT[i] = f2bf(fcw[k*256 + n]); return;
  }
  i -= 802816;
  if (i < 2560){
    blbr[i] = (i < 1280) ? bl[i] : br[i-1280];
    return;
  }
  i -= 2560;
  if (i < 32768){ c2wb[i] = f2bf(c2w[i]); return; }
  i -= 32768;
  if (i < 36864){ c3wb[i] = f2bf(c3w[i]); }
}

// ---------------- generic MFMA GEMM: C[m,n] = act(A[m,:]·B[n,:] + bias[n]) ----
__global__ __launch_bounds__(256) void gemm_k(const unsigned short* __restrict__ A,
              const unsigned short* __restrict__ B, const float* __restrict__ bias,
              unsigned short* __restrict__ C, int K, int ldc, int rowmul, int relu, int Nblk){
  __shared__ __align__(16) unsigned short As[64*32];
  __shared__ __align__(16) unsigned short Bs[64*32];
  int bid = blockIdx.x;
  int nb = bid % Nblk, mb = bid / Nblk;
  int t = threadIdx.x;
  int w = t >> 6, l = t & 63, lr = l & 15, lh = l >> 4;
  int sr = t >> 2, sq = t & 3;
  f32x4 acc[4];
  #pragma unroll
  for (int i=0;i<4;i++) acc[i] = (f32x4){0.f,0.f,0.f,0.f};
  int nkk = K >> 5;
  const size_t a_row = (size_t)(mb*64 + sr)*K;
  const size_t b_row = (size_t)(nb*64 + sr)*K;
  for (int kk=0;kk<nkk;kk++){
    uint4v av = *(const uint4v*)&A[a_row + kk*32 + sq*8];
    uint4v bv = *(const uint4v*)&B[b_row + kk*32 + sq*8];
    __syncthreads();
    *(uint4v*)((char*)As + ((sr*64 + sq*16) ^ ((sr&3)<<4))) = av;
    *(uint4v*)((char*)Bs + ((sr*64 + sq*16) ^ ((sr&3)<<4))) = bv;
    __syncthreads();
    int brow = w*16 + lr;
    bf16x8 bfr = *(const bf16x8*)((char*)Bs + ((brow*64 + lh*16) ^ ((brow&3)<<4)));
    #pragma unroll
    for (int mt=0;mt<4;mt++){
      int arow = mt*16 + lr;
      bf16x8 afr = *(const bf16x8*)((char*)As + ((arow*64 + lh*16) ^ ((arow&3)<<4)));
      acc[mt] = MFMA16(afr, bfr, acc[mt]);
    }
  }
  int col = nb*64 + w*16 + lr;
  float bn = bias[col];
  #pragma unroll
  for (int mt=0;mt<4;mt++){
    #pragma unroll
    for (int r=0;r<4;r++){
      int row = mb*64 + mt*16 + lh*4 + r;
      float v = acc[mt][r] + bn;
      if (relu) v = fmaxf(v, 0.f);
      C[(size_t)row*rowmul*ldc + col] = f2bf(v);
    }
  }
}

// ---------------- FC split-K GEMM: 112 blocks = 16 tiles x 7 K-slices, f32 partials ----
__global__ __launch_bounds__(256) void gemm_fc_k(const unsigned short* __restrict__ A,
              const unsigned short* __restrict__ B, float* __restrict__ P){
  __shared__ __align__(16) unsigned short As[64*32];
  __shared__ __align__(16) unsigned short Bs[64*32];
  int bid = blockIdx.x;
  int s = bid % 7, tile = bid / 7;
  int nb = tile & 3, mb = tile >> 2;
  int t = threadIdx.x;
  int w = t >> 6, l = t & 63, lr = l & 15, lh = l >> 4;
  int sr = t >> 2, sq = t & 3;
  f32x4 acc[4];
  #pragma unroll
  for (int i=0;i<4;i++) acc[i] = (f32x4){0.f,0.f,0.f,0.f};
  const int K = 3136;
  const size_t a_row = (size_t)(mb*64 + sr)*K;
  const size_t b_row = (size_t)(nb*64 + sr)*K;
  for (int kk = s*14; kk < s*14 + 14; kk++){
    uint4v av = *(const uint4v*)&A[a_row + kk*32 + sq*8];
    uint4v bv = *(const uint4v*)&B[b_row + kk*32 + sq*8];
    __syncthreads();
    *(uint4v*)((char*)As + ((sr*64 + sq*16) ^ ((sr&3)<<4))) = av;
    *(uint4v*)((char*)Bs + ((sr*64 + sq*16) ^ ((sr&3)<<4))) = bv;
    __syncthreads();
    int brow = w*16 + lr;
    bf16x8 bfr = *(const bf16x8*)((char*)Bs + ((brow*64 + lh*16) ^ ((brow&3)<<4)));
    #pragma unroll
    for (int mt=0;mt<4;mt++){
      int arow = mt*16 + lr;
      bf16x8 afr = *(const bf16x8*)((char*)As + ((arow*64 + lh*16) ^ ((arow&3)<<4)));
      acc[mt] = MFMA16(afr, bfr, acc[mt]);
    }
  }
  int col = nb*64 + w*16 + lr;
  #pragma unroll
  for (int mt=0;mt<4;mt++){
    #pragma unroll
    for (int r=0;r<4;r++){
      int row = mb*64 + mt*16 + lh*4 + r;
      P[(size_t)s*65536 + row*256 + col] = acc[mt][r];
    }
  }
}

// ---------------- FC reduce: sum 7 partials + bias + relu -> nemb node-0 rows ----
__global__ __launch_bounds__(256) void fc_red_k(const float* __restrict__ P,
              const float* __restrict__ fcb, unsigned short* __restrict__ nemb){
  int idx = blockIdx.x*256 + threadIdx.x;       // 65536 total
  int row = idx >> 8, col = idx & 255;
  float sum = fcb[col];
  #pragma unroll
  for (int k=0;k<7;k++) sum += P[k*65536 + idx];
  nemb[(size_t)row*25*256 + col] = f2bf(fmaxf(sum, 0.f));
}

// ---------------- mega kernel: blocks 0..191 = GRU (R9); 192..255 = full CNN chain ------
// CNN: block cb handles batches {cb, cb+64, cb+128, cb+192}; register-blocked convs,
//      4 x 256-thread sub-groups; intermediates in LDS; only conv3 out hits global.
// LDS overlay per batch iter:
//   [0..84672)      img f32       (phase1)   |  w2s bf16 [0..65536)+b2 (phase2)
//                                            |  w3s bf16 [0..73728)+b3 (phase3)
//   [74240..84608)  c2s bf16 (written phase2, read phase3)
//   [84672..109248) w1 f32 (persistent) [109248..109376) b1
//   [109376..134976) c1s bf16
__global__ __launch_bounds__(1024, 4)
void gruconv_k(const float* __restrict__ obs,
              const unsigned char* __restrict__ wfrag8,
              const unsigned short* __restrict__ mlpfrag,
              const float* __restrict__ mlpb,
              const float* __restrict__ bih, const float* __restrict__ bhh,
              unsigned short* __restrict__ nemb,
              const float* __restrict__ cin, const float* __restrict__ c1w,
              const float* __restrict__ c1b,
              const unsigned short* __restrict__ c2wb, const float* __restrict__ c2b,
              const unsigned short* __restrict__ c3wb, const float* __restrict__ c3b,
              unsigned short* __restrict__ c3o){
  __shared__ __align__(16) char smem[135040];

  const int t = threadIdx.x, blk = blockIdx.x;

  if (blk >= 192){
    // ================= CNN chain path =================
    float* img = (float*)smem;
    unsigned short* w2s = (unsigned short*)smem;
    float* b2  = (float*)(smem + 65536);
    unsigned short* w3s = (unsigned short*)smem;
    float* b3  = (float*)(smem + 73728);
    unsigned short* c2s = (unsigned short*)(smem + 74240);   // [64][9][9]
    float* w1  = (float*)(smem + 84672);
    float* b1  = (float*)(smem + 109248);
    unsigned short* c1s = (unsigned short*)(smem + 109376);  // [32][20][20]
    int cb = blk - 192;
    int q = t >> 8, t2 = t & 255;       // 4 sub-groups of 256
    for (int idx = t; idx < 6144; idx += 1024) w1[idx] = c1w[idx];
    if (t < 32) b1[t] = c1b[t];
    for (int i=0;i<4;i++){
      int b = cb + (i<<6);
      __syncthreads();                  // prev iter conv3 reads done; w1 load done (i=0)
      for (int idx = t; idx < 21168; idx += 1024) img[idx] = cin[(size_t)b*21168 + idx];
      __syncthreads();
      // conv1: [3,84,84] -> [32,20,20], k=8 s=4, relu (register-blocked, 4 outputs/iter)
      for (int p = t2; p < 800; p += 256){
        int oc = p / 25; int rem = p - oc*25;
        int oyq = rem / 5, og = rem - oyq*5;
        int oy = q*5 + oyq;
        float a0=b1[oc],a1=b1[oc],a2=b1[oc],a3=b1[oc];
        #pragma unroll
        for (int ic=0;ic<3;ic++){
          #pragma unroll
          for (int ky=0;ky<8;ky++){
            const float* row = &img[(ic*84 + oy*4+ky)*84 + og*16];
            float s[20];
            #pragma unroll
            for (int cc=0;cc<20;cc++) s[cc]=row[cc];
            const float* wp = &w1[(oc*3 + ic)*64 + ky*8];
            #pragma unroll
            for (int kx=0;kx<8;kx++){
              float wv = wp[kx];
              a0 += s[kx]*wv; a1 += s[4+kx]*wv; a2 += s[8+kx]*wv; a3 += s[12+kx]*wv;
            }
          }
        }
        int ob = (oc*20 + oy)*20 + og*4;
        c1s[ob+0]=f2bf(fmaxf(a0,0.f)); c1s[ob+1]=f2bf(fmaxf(a1,0.f));
        c1s[ob+2]=f2bf(fmaxf(a2,0.f)); c1s[ob+3]=f2bf(fmaxf(a3,0.f));
      }
      __syncthreads();                  // conv1 done; img dead
      for (int idx = t; idx < 32768; idx += 1024) w2s[idx] = c2wb[idx];
      if (t < 64) b2[t] = c2b[t];
      __syncthreads();
      // conv2: [32,20,20] -> [64,9,9], k=4 s=2, relu (3 outputs/iter, s[8] reuse)
      for (int p = t2; p < 432; p += 256){
        int ocl = p / 27; int rem = p - ocl*27;
        int oy = rem / 3, og = rem - oy*3;
        int oc = q*16 + ocl;
        float a0=b2[oc],a1=b2[oc],a2=b2[oc];
        #pragma unroll 4
        for (int ic=0;ic<32;ic++){
          #pragma unroll
          for (int ky=0;ky<4;ky++){
            const unsigned short* row = &c1s[(ic*20 + oy*2+ky)*20 + og*6];
            float s[8];
            #pragma unroll
            for (int cc=0;cc<8;cc++) s[cc]=bf2f(row[cc]);
            const unsigned short* wp = &c2wb[((oc*32+ic)*4+ky)*4];
            const unsigned short* wl2 = &w2s[((oc*32+ic)*4+ky)*4];
            #pragma unroll
            for (int kx=0;kx<4;kx++){
              float wv = bf2f(wl2[kx]);
              a0 += s[kx]*wv; a1 += s[2+kx]*wv; a2 += s[4+kx]*wv;
            }
            (void)wp;
          }
        }
        int ob = (oc*9 + oy)*9 + og*3;
        c2s[ob+0]=f2bf(fmaxf(a0,0.f)); c2s[ob+1]=f2bf(fmaxf(a1,0.f)); c2s[ob+2]=f2bf(fmaxf(a2,0.f));
      }
      __syncthreads();                  // conv2 done; w2s dead
      for (int idx = t; idx < 36864; idx += 1024) w3s[idx] = c3wb[idx];
      if (t < 64) b3[t] = c3b[t];
      __syncthreads();
      // conv3: [64,9,9] -> flat [64,7,7], k=3 s=1, relu -> global (4 outputs/iter, s[6])
      for (int p = t2; p < 224; p += 256){
        int ocl = p / 14; int rem = p - ocl*14;
        int oy = rem >> 1, og = rem & 1;
        int ox0 = og*4; int nx = og ? 3 : 4;
        int oc = q*16 + ocl;
        float a[4]; a[0]=a[1]=a[2]=a[3]=b3[oc];
        for (int ic=0;ic<64;ic++){
          #pragma unroll
          for (int ky=0;ky<3;ky++){
            const unsigned short* row = &c2s[(ic*9 + oy+ky)*9 + ox0];
            float s[6];
            #pragma unroll
            for (int cc=0;cc<6;cc++) s[cc] = (ox0+cc < 9) ? bf2f(row[cc]) : 0.f;
            const unsigned short* wp = &w3s[((oc*64+ic)*3+ky)*3];
            #pragma unroll
            for (int kx=0;kx<3;kx++){
              float wv = bf2f(wp[kx]);
              #pragma unroll
              for (int jj=0;jj<4;jj++) a[jj] += s[jj+kx]*wv;
            }
          }
        }
        size_t ob = (size_t)b*3136 + oc*49 + oy*7 + ox0;
        #pragma unroll
        for (int jj=0;jj<4;jj++) if (jj < nx) c3o[ob+jj] = f2bf(fmaxf(a[jj],0.f));
      }
    }
    return;
  }

  // ================= GRU path (exact R9) =================
  unsigned short* obsA = (unsigned short*)smem;
  unsigned char* e8_0 = (unsigned char*)(smem + 2048);
  unsigned char* e8_1 = (unsigned char*)(smem + 10240);
  unsigned char* h8   = (unsigned char*)(smem + 18432);

  obsA[t & 1023] = 0;
  for (int j = t; j < 8192; j += 1024) h8[j] = 0;

  const int w = t >> 6, l = t & 63, lr = l & 15, lh = l >> 4;
  const int jcol = w*16 + lr;
  const float bR  = bih[jcol]     + bhh[jcol];
  const float bZ  = bih[256+jcol] + bhh[256+jcol];
  const float bXN = bih[512+jcol];
  const float bHN = bhh[512+jcol];
  const float bMb = mlpb[jcol];
  const bf16x8 bMLP = *(const bf16x8*)(mlpfrag + w*512 + l*8);

  const unsigned char* wb8 = wfrag8 + w*24576 + l*16;

  const int srow = t >> 2, sk4 = t & 3;
  int rrS = blk*32 + srow; int bS = rrS/24, ndS = 1 + (rrS - bS*24);
  const float* obase4 = obs + (size_t)(bS*25 + ndS)*800 + sk4*4;
  const int obyte = (srow*64 + sk4*8) ^ ((srow&3)<<4);

  const int a8off = lr*256 + lh*8;
  const int xr8 = lr << 3;
  const int o16 = lh*16;
  const int oa0b = (lr*64 + o16) ^ ((lr&3)<<4);
  const int oa1b = ((16+lr)*64 + o16) ^ ((lr&3)<<4);
  const int hw0 = jcol;
  const float S = 1.f/256.f;

  f32x4 hs0 = (f32x4){0.f,0.f,0.f,0.f};
  f32x4 hs1 = (f32x4){0.f,0.f,0.f,0.f};

#define EMB_COMPUTE(DST) { \
  f32x4 e0 = (f32x4){0.f,0.f,0.f,0.f}, e1 = (f32x4){0.f,0.f,0.f,0.f}; \
  bf16x8 oa0 = *(const bf16x8*)((char*)obsA + oa0b); \
  bf16x8 oa1 = *(const bf16x8*)((char*)obsA + oa1b); \
  e0 = MFMA16(oa0, bMLP, e0); \
  e1 = MFMA16(oa1, bMLP, e1); \
  _Pragma("unroll") \
  for (int r=0;r<4;r++){ \
    int m = lh*4 + r; \
    (DST)[(m*256 + hw0) ^ ((m&15)<<3)] = f2fp8(fmaxf(e0[r] + bMb, 0.f)*16.f); \
    int m2 = m + 16; \
    (DST)[(m2*256 + hw0) ^ ((m2&15)<<3)] = f2fp8(fmaxf(e1[r] + bMb, 0.f)*16.f); \
  } }

  __syncthreads();
  if (t < 128){
    float4v ov = *(const float4v*)(obase4);
    uint2v pk;
    pk[0] = (unsigned)f2bf(ov[0]) | ((unsigned)f2bf(ov[1]) << 16);
    pk[1] = (unsigned)f2bf(ov[2]) | ((unsigned)f2bf(ov[3]) << 16);
    *(uint2v*)((char*)obsA + obyte) = pk;
  }
  __syncthreads();
  EMB_COMPUTE(e8_0)
  __syncthreads();

  for (int step=0; step<50; step++){
    const unsigned char* ebuf = (step & 1) ? e8_1 : e8_0;
    unsigned char* nbuf = (step & 1) ? e8_0 : e8_1;
    const bool stg = (t < 128) && (step < 49);
    float4v ov;
    if (stg) ov = *(const float4v*)(obase4 + (size_t)(step+1)*16);

    f32x4 aR0=(f32x4){0,0,0,0}, aR1=(f32x4){0,0,0,0};
    f32x4 aZ0=(f32x4){0,0,0,0}, aZ1=(f32x4){0,0,0,0};
    f32x4 aN0=(f32x4){0,0,0,0}, aN1=(f32x4){0,0,0,0};
    f32x4 aM0=(f32x4){0,0,0,0}, aM1=(f32x4){0,0,0,0};
    __builtin_amdgcn_s_setprio(1);
    #pragma unroll 2
    for (int kkp=0;kkp<4;kkp++){
      const unsigned char* wk8 = wb8 + kkp*6144;
      long2v wIR = *(const long2v*)(wk8);
      long2v wIZ = *(const long2v*)(wk8 + 1024);
      long2v wIN = *(const long2v*)(wk8 + 2048);
      long2v wHR = *(const long2v*)(wk8 + 3072);
      long2v wHZ = *(const long2v*)(wk8 + 4096);
      long2v wHN = *(const long2v*)(wk8 + 5120);
      {
        int kk = kkp*2;
        int ab = a8off + kk*32;
        long eA0 = *(const long*)(ebuf + (ab ^ xr8));
        long eA1 = *(const long*)(ebuf + ((ab + 4096) ^ xr8));
        long hA0 = *(const long*)(h8 + (ab ^ xr8));
        long hA1 = *(const long*)(h8 + ((ab + 4096) ^ xr8));
        aR0 = MFMA8(eA0, wIR[0], aR0);  aR0 = MFMA8(hA0, wHR[0], aR0);
        aR1 = MFMA8(eA1, wIR[0], aR1);  aR1 = MFMA8(hA1, wHR[0], aR1);
        aZ0 = MFMA8(eA0, wIZ[0], aZ0);  aZ0 = MFMA8(hA0, wHZ[0], aZ0);
        aZ1 = MFMA8(eA1, wIZ[0], aZ1);  aZ1 = MFMA8(hA1, wHZ[0], aZ1);
        aN0 = MFMA8(eA0, wIN[0], aN0);  aN1 = MFMA8(eA1, wIN[0], aN1);
        aM0 = MFMA8(hA0, wHN[0], aM0);  aM1 = MFMA8(hA1, wHN[0], aM1);
      }
      {
        int kk = kkp*2 + 1;
        int ab = a8off + kk*32;
        long eA0 = *(const long*)(ebuf + (ab ^ xr8));
        long eA1 = *(const long*)(ebuf + ((ab + 4096) ^ xr8));
        long hA0 = *(const long*)(h8 + (ab ^ xr8));
        long hA1 = *(const long*)(h8 + ((ab + 4096) ^ xr8));
        aR0 = MFMA8(eA0, wIR[1], aR0);  aR0 = MFMA8(hA0, wHR[1], aR0);
        aR1 = MFMA8(eA1, wIR[1], aR1);  aR1 = MFMA8(hA1, wHR[1], aR1);
        aZ0 = MFMA8(eA0, wIZ[1], aZ0);  aZ0 = MFMA8(hA0, wHZ[1], aZ0);
        aZ1 = MFMA8(eA1, wIZ[1], aZ1);  aZ1 = MFMA8(hA1, wHZ[1], aZ1);
        aN0 = MFMA8(eA0, wIN[1], aN0);  aN1 = MFMA8(eA1, wIN[1], aN1);
        aM0 = MFMA8(hA0, wHN[1], aM0);  aM1 = MFMA8(hA1, wHN[1], aM1);
      }
    }
    __builtin_amdgcn_s_setprio(0);
    if (stg){
      uint2v pk;
      pk[0] = (unsigned)f2bf(ov[0]) | ((unsigned)f2bf(ov[1]) << 16);
      pk[1] = (unsigned)f2bf(ov[2]) | ((unsigned)f2bf(ov[3]) << 16);
      *(uint2v*)((char*)obsA + obyte) = pk;
    }
    __syncthreads();
    if (step < 49){
      EMB_COMPUTE(nbuf)
    }
    #pragma unroll
    for (int mt=0;mt<2;mt++){
      f32x4 vR = mt ? aR1 : aR0;
      f32x4 vZ = mt ? aZ1 : aZ0;
      f32x4 vN = mt ? aN1 : aN0;
      f32x4 vM = mt ? aM1 : aM0;
      #pragma unroll
      for (int r=0;r<4;r++){
        float rp = vR[r]*S + bR;
        float zp = vZ[r]*S + bZ;
        float xn = vN[r]*S + bXN;
        float hn = vM[r]*S + bHN;
        float rg = 1.f/(1.f + __expf(-rp));
        float zg = 1.f/(1.f + __expf(-zp));
        float arg = xn + rg*hn;
        float e2 = __expf(2.f*arg);
        float nv = (e2 - 1.f)/(e2 + 1.f);
        float hold = mt ? hs1[r] : hs0[r];
        float hnew = (1.f - zg)*nv + zg*hold;
        if (mt) hs1[r] = hnew; else hs0[r] = hnew;
        int m = mt*16 + lh*4 + r;
        h8[(m*256 + hw0) ^ ((m&15)<<3)] = f2fp8(hnew*16.f);
        if (step == 49){
          int rr = blk*32 + m; int b = rr/24; int nd = 1 + (rr - b*24);
          nemb[(size_t)(b*25+nd)*256 + jcol] = f2bf(hnew);
        }
      }
    }
    __syncthreads();
  }
#undef EMB_COMPUTE
}

// ---------------- GAT scores + softmax + node0 out + dueling head ----------------
__global__ __launch_bounds__(256) void gat_k(const int* __restrict__ edges,
              const unsigned short* __restrict__ glgr,
              const float* __restrict__ att, const float* __restrict__ gbias,
              const float* __restrict__ hidw, const float* __restrict__ hidb,
              const float* __restrict__ outw, const float* __restrict__ outb,
              const float* __restrict__ advw, const float* __restrict__ advb,
              float* __restrict__ out){
  __shared__ int src_s[125], dst_s[125];
  __shared__ __align__(16) float att_s[1280];
  __shared__ float sc[125][5], al[125][5];
  __shared__ float mx[25][5], dn[25][5];
  __shared__ float g0[256], hh[256];
  __shared__ float adv_s[8], v_s;
  __shared__ int e0[125]; __shared__ int ne0;

  int b = blockIdx.x, t = threadIdx.x;
  if (t < 100){ src_s[t] = edges[b*200 + t]; dst_s[t] = edges[b*200 + 100 + t]; }
  else if (t < 125){ src_s[t] = t - 100; dst_s[t] = t - 100; }
  for (int j = t; j < 1280; j += 256) att_s[j] = att[j];
  __syncthreads();
  if (t == 0){ int c = 0; for (int e=0;e<125;e++) if (dst_s[e]==0) e0[c++]=e; ne0 = c; }
  const unsigned short* gbase = glgr + (size_t)b*25*2560;
  for (int p = t; p < 625; p += 256){
    int e = p/5, h = p - 5*(p/5);
    const unsigned short* glp = gbase + src_s[e]*2560 + h*256;
    const unsigned short* grp = gbase + dst_s[e]*2560 + 1280 + h*256;
    const float* ap = &att_s[h*256];
    float acc = 0.f;
    #pragma unroll 4
    for (int c=0;c<256;c+=8){
      uint4v gu = *(const uint4v*)&glp[c];
      uint4v ru = *(const uint4v*)&grp[c];
      #pragma unroll
      for (int q=0;q<4;q++){
        float s0 = bflo(gu[q]) + bflo(ru[q]);
        float s1 = bfhi(gu[q]) + bfhi(ru[q]);
        s0 = (s0 > 0.f) ? s0 : 0.2f*s0;
        s1 = (s1 > 0.f) ? s1 : 0.2f*s1;
        acc += s0*ap[c+2*q] + s1*ap[c+2*q+1];
      }
    }
    sc[e][h] = acc;
  }
  __syncthreads();
  if (t < 125){
    int j = t/5, h = t - 5*(t/5);
    float m = -1e30f;
    for (int e=0;e<125;e++) if (dst_s[e]==j) m = fmaxf(m, sc[e][h]);
    float d = 0.f;
    for (int e=0;e<125;e++) if (dst_s[e]==j) d += __expf(sc[e][h]-m);
    mx[j][h] = m; dn[j][h] = d;
  }
  __syncthreads();
  for (int p = t; p < 625; p += 256){
    int e = p/5, h = p - 5*(p/5);
    int dd = dst_s[e];
    al[e][h] = __expf(sc[e][h] - mx[dd][h]) / dn[dd][h];
  }
  __syncthreads();
  if (t < 101){
    out[2048 + b*101 + t] = (al[t][0]+al[t][1]+al[t][2]+al[t][3]+al[t][4])*0.2f;
  }
  {
    float acc = 0.f;
    for (int x=0;x<ne0;x++){
      int e = e0[x]; int s = src_s[e];
      const unsigned short* glp = gbase + s*2560 + t;
      #pragma unroll
      for (int h=0;h<5;h++) acc += al[e][h]*bf2f(glp[h*256]);
    }
    g0[t] = acc*0.2f + gbias[t];
  }
  __syncthreads();
  {
    float acc = hidb[t];
    for (int k=0;k<256;k++) acc += g0[k]*hidw[k*256+t];
    hh[t] = fmaxf(acc, 0.f);
  }
  __syncthreads();
  if (t < 8){
    float acc = advb[t];
    for (int k=0;k<256;k++) acc += hh[k]*advw[k*8+t];
    adv_s[t] = acc;
  } else if (t == 8){
    float acc = outb[0];
    for (int k=0;k<256;k++) acc += hh[k]*outw[k];
    v_s = acc;
  }
  __syncthreads();
  if (t < 8){
    float m = adv_s[0]+adv_s[1]+adv_s[2]+adv_s[3]+adv_s[4]+adv_s[5]+adv_s[6]+adv_s[7];
    out[b*8+t] = v_s + adv_s[t] - m*0.125f;
  }
}

extern "C" void kernel_launch(void* const* d_in, const int* in_sizes, int n_in,
                              void* d_out, int out_size, void* d_ws, size_t ws_size,
                              hipStream_t stream){
  const float* obs     = (const float*)d_in[0];
  const float* obs_map = (const float*)d_in[1];
  const int*   edges   = (const int*)d_in[2];
  const float* mlp_w = (const float*)d_in[4];
  const float* mlp_b = (const float*)d_in[5];
  const float* c1w = (const float*)d_in[6];  const float* c1b = (const float*)d_in[7];
  const float* c2w = (const float*)d_in[8];  const float* c2b = (const float*)d_in[9];
  const float* c3w = (const float*)d_in[10]; const float* c3b = (const float*)d_in[11];
  const float* fcw = (const float*)d_in[12]; const float* fcb = (const float*)d_in[13];
  const float* wih = (const float*)d_in[14]; const float* whh = (const float*)d_in[15];
  const float* bih = (const float*)d_in[16]; const float* bhh = (const float*)d_in[17];
  const float* gwl = (const float*)d_in[18]; const float* gbl = (const float*)d_in[19];
  const float* gwr = (const float*)d_in[20]; const float* gbr = (const float*)d_in[21];
  const float* gatt = (const float*)d_in[22]; const float* gbias = (const float*)d_in[23];
  const float* hidw = (const float*)d_in[24]; const float* hidb = (const float*)d_in[25];
  const float* outw = (const float*)d_in[26]; const float* outb = (const float*)d_in[27];
  const float* advw = (const float*)d_in[28]; const float* advb = (const float*)d_in[29];
  float* out = (float*)d_out;
  char* ws = (char*)d_ws;

  // workspace layout (c3o + fcpart aliased under glgr; consumed before glgr write)
  unsigned short* c3o  = (unsigned short*)(ws + 0);          // 1,605,632 B
  float*          fcpart = (float*)(ws + 16000000);          // 1,835,008 B (inside glgr window)
  unsigned short* glgr = (unsigned short*)(ws + 0);          // 32,768,000 B
  size_t o = 32768000;
  unsigned short* nemb    = (unsigned short*)(ws + o); o += 3276800;
  unsigned char*  wfrag8  = (unsigned char*)(ws + o);  o += 393216;
  unsigned short* mlpfrag = (unsigned short*)(ws + o); o += 16384;
  unsigned short* wlrT    = (unsigned short*)(ws + o); o += 1310720;
  unsigned short* fcwT    = (unsigned short*)(ws + o); o += 1605632;
  float* blbr             = (float*)(ws + o); o += 10240;
  unsigned short* c2wb    = (unsigned short*)(ws + o); o += 65536;
  unsigned short* c3wb    = (unsigned short*)(ws + o); o += 73728;

  prep_k<<<7546, 256, 0, stream>>>(wih, whh, gwl, gwr, gbl, gbr, fcw, mlp_w, c2w, c3w,
                                   wfrag8, mlpfrag, wlrT, fcwT, blbr, c2wb, c3wb);
  gruconv_k<<<256, 1024, 0, stream>>>(obs, wfrag8, mlpfrag, mlp_b, bih, bhh, nemb,
                                      obs_map, c1w, c1b, c2wb, c2b, c3wb, c3b, c3o);
  gemm_fc_k<<<112, 256, 0, stream>>>(c3o, fcwT, fcpart);                          // FC split-K
  fc_red_k<<<256, 256, 0, stream>>>(fcpart, fcb, nemb);                           // -> node 0
  gemm_k<<<4000, 256, 0, stream>>>(nemb, wlrT, blbr, glgr, 256, 2560, 1, 0, 40);  // gl|gr
  gat_k<<<256, 256, 0, stream>>>(edges, glgr, gatt, gbias, hidw, hidb, outw, outb, advw, advb, out);
}

// Round 14
// 750.623 us; speedup vs baseline: 3.0904x; 1.7774x over previous
//
#include <hip/hip_runtime.h>
#include <cstdint>

typedef __attribute__((ext_vector_type(8))) __bf16 bf16x8;
typedef __attribute__((ext_vector_type(4))) float f32x4;
typedef __attribute__((ext_vector_type(4))) unsigned int uint4v;
typedef __attribute__((ext_vector_type(2))) unsigned int uint2v;
typedef __attribute__((ext_vector_type(4))) float float4v;
typedef __attribute__((ext_vector_type(2))) long long2v;

__device__ __forceinline__ unsigned short f2bf(float x){
  union { float f; unsigned u; } v; v.f = x;
  unsigned r = v.u + 0x7FFFu + ((v.u >> 16) & 1u);
  return (unsigned short)(r >> 16);
}
__device__ __forceinline__ float bf2f(unsigned short h){
  union { unsigned u; float f; } v; v.u = ((unsigned)h) << 16;
  return v.f;
}
__device__ __forceinline__ float bflo(unsigned u){
  union { unsigned x; float f; } v; v.x = u << 16; return v.f;
}
__device__ __forceinline__ float bfhi(unsigned u){
  union { unsigned x; float f; } v; v.x = u & 0xFFFF0000u; return v.f;
}
__device__ __forceinline__ f32x4 MFMA16(bf16x8 a, bf16x8 b, f32x4 c){
  return __builtin_amdgcn_mfma_f32_16x16x32_bf16(a, b, c, 0, 0, 0);
}
__device__ __forceinline__ f32x4 MFMA8(long a, long b, f32x4 c){
  return __builtin_amdgcn_mfma_f32_16x16x32_fp8_fp8(a, b, c, 0, 0, 0);
}
__device__ __forceinline__ unsigned char f2fp8(float x){
  int p = __builtin_amdgcn_cvt_pk_fp8_f32(x, x, 0, false);
  return (unsigned char)(p & 0xFF);
}

// ---------------- prep: all branches coalesced ----------------
__global__ __launch_bounds__(256) void prep_k(
    const float* __restrict__ wih, const float* __restrict__ whh,
    const float* __restrict__ bl, const float* __restrict__ br,
    const float* __restrict__ mlpw,
    const float* __restrict__ c2w, const float* __restrict__ c3w,
    unsigned char* __restrict__ wfrag8, unsigned short* __restrict__ mlpfrag,
    float* __restrict__ blbr,
    unsigned short* __restrict__ c2wb, unsigned short* __restrict__ c3wb){
  int i = blockIdx.x*256 + threadIdx.x;
  if (i < 393216){
    int b16 = i & 15;
    int l   = (i >> 4) & 63;
    int chunk = i >> 10;           // (w*4+kkp)*6+mg
    int wkp = chunk / 6;
    int mg  = chunk - 6*wkp;
    int w = wkp >> 2, kkp = wkp & 3;
    int ks = b16 >> 3, e = b16 & 7;
    int kk = kkp*2 + ks;
    int mat = mg / 3, g = mg - 3*(mg/3);
    int n = g*256 + w*16 + (l & 15);
    int k = kk*32 + (l >> 4)*8 + e;
    float v = 16.f * (mat ? whh[n*256 + k] : wih[n*256 + k]);
    wfrag8[i] = f2fp8(v);
    return;
  }
  i -= 393216;
  if (i < 8192){
    int w = i >> 9;
    int r4 = i & 511;
    int l = r4 >> 3, e = r4 & 7;
    int n = w*16 + (l & 15);
    int k = (l >> 4)*8 + e;
    mlpfrag[i] = (k < 16) ? f2bf(mlpw[k*256 + n]) : (unsigned short)0;
    return;
  }
  i -= 8192;
  if (i < 2560){
    blbr[i] = (i < 1280) ? bl[i] : br[i-1280];
    return;
  }
  i -= 2560;
  if (i < 32768){ c2wb[i] = f2bf(c2w[i]); return; }
  i -= 32768;
  if (i < 36864){ c3wb[i] = f2bf(c3w[i]); }
}

// ---------------- LDS-tiled transposes (coalesced both sides) ----------------
// fcw [3136][256] f32 -> fcwT [256][3136] bf16 ; 196 blocks = 49 k-tiles x 4 n-tiles
__global__ __launch_bounds__(256) void tr_fc_k(const float* __restrict__ fcw,
              unsigned short* __restrict__ fcwT){
  __shared__ float tile[64][65];
  int bid = blockIdx.x, t = threadIdx.x;
  int ti = bid >> 2, tj = bid & 3;
  for (int idx = t; idx < 4096; idx += 256){
    int r = idx >> 6, c = idx & 63;
    tile[r][c] = fcw[(size_t)(ti*64 + r)*256 + tj*64 + c];
  }
  __syncthreads();
  for (int idx = t; idx < 4096; idx += 256){
    int r = idx >> 6, c = idx & 63;
    fcwT[(size_t)(tj*64 + r)*3136 + ti*64 + c] = f2bf(tile[c][r]);
  }
}

// wl/wr [256][1280] f32 -> wlrT [2560][256] bf16 ; 160 blocks = 2 mats x 4 k x 20 n
__global__ __launch_bounds__(256) void tr_wlr_k(const float* __restrict__ wl,
              const float* __restrict__ wr, unsigned short* __restrict__ wlrT){
  __shared__ float tile[64][65];
  int bid = blockIdx.x, t = threadIdx.x;
  int m = bid / 80; int rem = bid - m*80;
  int tk = rem / 20, tn = rem - tk*20;
  const float* src = m ? wr : wl;
  for (int idx = t; idx < 4096; idx += 256){
    int r = idx >> 6, c = idx & 63;
    tile[r][c] = src[(size_t)(tk*64 + r)*1280 + tn*64 + c];
  }
  __syncthreads();
  for (int idx = t; idx < 4096; idx += 256){
    int r = idx >> 6, c = idx & 63;
    wlrT[(size_t)(m*1280 + tn*64 + r)*256 + tk*64 + c] = f2bf(tile[c][r]);
  }
}

// ---------------- conv23: fused conv2+conv3 per batch, LDS intermediates ----------
// 256 blocks x 1024 threads (4 sub-groups q of 256); exact standalone loop bodies.
__global__ __launch_bounds__(1024) void conv23_k(const unsigned short* __restrict__ c1o,
              const unsigned short* __restrict__ c2wb, const float* __restrict__ c2b,
              const unsigned short* __restrict__ c3wb, const float* __restrict__ c3b,
              unsigned short* __restrict__ c3o){
  __shared__ __align__(16) char cs[102016];
  unsigned short* in_s = (unsigned short*)cs;            // [32][20][20] = 25600 B
  unsigned short* w2s  = (unsigned short*)(cs + 25600);  // 65536 B
  float* b2            = (float*)(cs + 91136);           // 256 B
  unsigned short* c2s  = (unsigned short*)(cs + 91392);  // [64][9][9] = 10368 B
  unsigned short* w3s  = (unsigned short*)cs;            // 73728 B (overlay, phase B)
  float* b3            = (float*)(cs + 101760);          // 256 B
  int b = blockIdx.x, t = threadIdx.x;
  int q = t >> 8, t2 = t & 255;
  for (int idx = t; idx < 12800; idx += 1024) in_s[idx] = c1o[(size_t)b*12800 + idx];
  for (int idx = t; idx < 32768; idx += 1024) w2s[idx] = c2wb[idx];
  if (t < 64) b2[t] = c2b[t];
  if (t >= 64 && t < 128) b3[t-64] = c3b[t-64];
  __syncthreads();
  // conv2: [32,20,20] -> [64,9,9], k=4 s=2, relu (oc = q*16+ocl)
  for (int p = t2; p < 432; p += 256){
    int ocl = p / 27; int rem = p - ocl*27;
    int oy = rem / 3, og = rem - oy*3;
    int oc = q*16 + ocl;
    float a0=b2[oc],a1=b2[oc],a2=b2[oc];
    #pragma unroll 4
    for (int ic=0;ic<32;ic++){
      #pragma unroll
      for (int ky=0;ky<4;ky++){
        const unsigned short* row = &in_s[(ic*20 + oy*2+ky)*20 + og*6];
        float s[8];
        #pragma unroll
        for (int cc=0;cc<8;cc++) s[cc]=bf2f(row[cc]);
        const unsigned short* wp = &w2s[((oc*32+ic)*4+ky)*4];
        #pragma unroll
        for (int kx=0;kx<4;kx++){
          float wv = bf2f(wp[kx]);
          a0 += s[kx]*wv; a1 += s[2+kx]*wv; a2 += s[4+kx]*wv;
        }
      }
    }
    int ob = (oc*9 + oy)*9 + og*3;
    c2s[ob+0]=f2bf(fmaxf(a0,0.f)); c2s[ob+1]=f2bf(fmaxf(a1,0.f)); c2s[ob+2]=f2bf(fmaxf(a2,0.f));
  }
  __syncthreads();                  // conv2 done; in_s/w2s dead
  for (int idx = t; idx < 36864; idx += 1024) w3s[idx] = c3wb[idx];
  __syncthreads();
  // conv3: [64,9,9] -> flat [64,7,7], k=3 s=1, relu -> global
  for (int p = t2; p < 224; p += 256){
    int ocl = p / 14; int rem = p - ocl*14;
    int oy = rem >> 1, og = rem & 1;
    int ox0 = og*4; int nx = og ? 3 : 4;
    int oc = q*16 + ocl;
    float a[4]; a[0]=a[1]=a[2]=a[3]=b3[oc];
    for (int ic=0;ic<64;ic++){
      #pragma unroll
      for (int ky=0;ky<3;ky++){
        const unsigned short* row = &c2s[(ic*9 + oy+ky)*9 + ox0];
        float s[6];
        #pragma unroll
        for (int cc=0;cc<6;cc++) s[cc] = (ox0+cc < 9) ? bf2f(row[cc]) : 0.f;
        const unsigned short* wp = &w3s[((oc*64+ic)*3+ky)*3];
        #pragma unroll
        for (int kx=0;kx<3;kx++){
          float wv = bf2f(wp[kx]);
          #pragma unroll
          for (int jj=0;jj<4;jj++) a[jj] += s[jj+kx]*wv;
        }
      }
    }
    size_t ob = (size_t)b*3136 + oc*49 + oy*7 + ox0;
    #pragma unroll
    for (int jj=0;jj<4;jj++) if (jj < nx) c3o[ob+jj] = f2bf(fmaxf(a[jj],0.f));
  }
}

// ---------------- generic MFMA GEMM: C[m,n] = act(A[m,:]·B[n,:] + bias[n]) ----
__global__ __launch_bounds__(256) void gemm_k(const unsigned short* __restrict__ A,
              const unsigned short* __restrict__ B, const float* __restrict__ bias,
              unsigned short* __restrict__ C, int K, int ldc, int rowmul, int relu, int Nblk){
  __shared__ __align__(16) unsigned short As[64*32];
  __shared__ __align__(16) unsigned short Bs[64*32];
  int bid = blockIdx.x;
  int nb = bid % Nblk, mb = bid / Nblk;
  int t = threadIdx.x;
  int w = t >> 6, l = t & 63, lr = l & 15, lh = l >> 4;
  int sr = t >> 2, sq = t & 3;
  f32x4 acc[4];
  #pragma unroll
  for (int i=0;i<4;i++) acc[i] = (f32x4){0.f,0.f,0.f,0.f};
  int nkk = K >> 5;
  const size_t a_row = (size_t)(mb*64 + sr)*K;
  const size_t b_row = (size_t)(nb*64 + sr)*K;
  for (int kk=0;kk<nkk;kk++){
    uint4v av = *(const uint4v*)&A[a_row + kk*32 + sq*8];
    uint4v bv = *(const uint4v*)&B[b_row + kk*32 + sq*8];
    __syncthreads();
    *(uint4v*)((char*)As + ((sr*64 + sq*16) ^ ((sr&3)<<4))) = av;
    *(uint4v*)((char*)Bs + ((sr*64 + sq*16) ^ ((sr&3)<<4))) = bv;
    __syncthreads();
    int brow = w*16 + lr;
    bf16x8 bfr = *(const bf16x8*)((char*)Bs + ((brow*64 + lh*16) ^ ((brow&3)<<4)));
    #pragma unroll
    for (int mt=0;mt<4;mt++){
      int arow = mt*16 + lr;
      bf16x8 afr = *(const bf16x8*)((char*)As + ((arow*64 + lh*16) ^ ((arow&3)<<4)));
      acc[mt] = MFMA16(afr, bfr, acc[mt]);
    }
  }
  int col = nb*64 + w*16 + lr;
  float bn = bias[col];
  #pragma unroll
  for (int mt=0;mt<4;mt++){
    #pragma unroll
    for (int r=0;r<4;r++){
      int row = mb*64 + mt*16 + lh*4 + r;
      float v = acc[mt][r] + bn;
      if (relu) v = fmaxf(v, 0.f);
      C[(size_t)row*rowmul*ldc + col] = f2bf(v);
    }
  }
}

// ---------------- FC split-K GEMM: 112 blocks = 16 tiles x 7 K-slices, f32 partials ----
__global__ __launch_bounds__(256) void gemm_fc_k(const unsigned short* __restrict__ A,
              const unsigned short* __restrict__ B, float* __restrict__ P){
  __shared__ __align__(16) unsigned short As[64*32];
  __shared__ __align__(16) unsigned short Bs[64*32];
  int bid = blockIdx.x;
  int s = bid % 7, tile = bid / 7;
  int nb = tile & 3, mb = tile >> 2;
  int t = threadIdx.x;
  int w = t >> 6, l = t & 63, lr = l & 15, lh = l >> 4;
  int sr = t >> 2, sq = t & 3;
  f32x4 acc[4];
  #pragma unroll
  for (int i=0;i<4;i++) acc[i] = (f32x4){0.f,0.f,0.f,0.f};
  const int K = 3136;
  const size_t a_row = (size_t)(mb*64 + sr)*K;
  const size_t b_row = (size_t)(nb*64 + sr)*K;
  for (int kk = s*14; kk < s*14 + 14; kk++){
    uint4v av = *(const uint4v*)&A[a_row + kk*32 + sq*8];
    uint4v bv = *(const uint4v*)&B[b_row + kk*32 + sq*8];
    __syncthreads();
    *(uint4v*)((char*)As + ((sr*64 + sq*16) ^ ((sr&3)<<4))) = av;
    *(uint4v*)((char*)Bs + ((sr*64 + sq*16) ^ ((sr&3)<<4))) = bv;
    __syncthreads();
    int brow = w*16 + lr;
    bf16x8 bfr = *(const bf16x8*)((char*)Bs + ((brow*64 + lh*16) ^ ((brow&3)<<4)));
    #pragma unroll
    for (int mt=0;mt<4;mt++){
      int arow = mt*16 + lr;
      bf16x8 afr = *(const bf16x8*)((char*)As + ((arow*64 + lh*16) ^ ((arow&3)<<4)));
      acc[mt] = MFMA16(afr, bfr, acc[mt]);
    }
  }
  int col = nb*64 + w*16 + lr;
  #pragma unroll
  for (int mt=0;mt<4;mt++){
    #pragma unroll
    for (int r=0;r<4;r++){
      int row = mb*64 + mt*16 + lh*4 + r;
      P[(size_t)s*65536 + row*256 + col] = acc[mt][r];
    }
  }
}

// ---------------- FC reduce: sum 7 partials + bias + relu -> nemb node-0 rows ----
__global__ __launch_bounds__(256) void fc_red_k(const float* __restrict__ P,
              const float* __restrict__ fcb, unsigned short* __restrict__ nemb){
  int idx = blockIdx.x*256 + threadIdx.x;       // 65536 total
  int row = idx >> 8, col = idx & 255;
  float sum = fcb[col];
  #pragma unroll
  for (int k=0;k<7;k++) sum += P[k*65536 + idx];
  nemb[(size_t)row*25*256 + col] = f2bf(fmaxf(sum, 0.f));
}

// ---------------- mega kernel: blocks 0..191 = GRU (R9); 192..447 = conv1 (R11) --------
__global__ __launch_bounds__(1024, 4)
void gruconv_k(const float* __restrict__ obs,
              const unsigned char* __restrict__ wfrag8,
              const unsigned short* __restrict__ mlpfrag,
              const float* __restrict__ mlpb,
              const float* __restrict__ bih, const float* __restrict__ bhh,
              unsigned short* __restrict__ nemb,
              const float* __restrict__ cin, const float* __restrict__ c1w,
              const float* __restrict__ c1b, unsigned short* __restrict__ c1o){
  __shared__ __align__(16) char smem[121984];

  const int t = threadIdx.x, blk = blockIdx.x;

  if (blk >= 192){
    // ================= conv1 path =================
    float* in_s = (float*)smem;                     // [4][3][24][84] = 96768 B
    float* w_s  = (float*)(smem + 96768);           // [32][3][8][8]  = 24576 B
    float* b_s  = (float*)(smem + 121344);          // [32]
    int b = blk - 192;
    int q = t >> 8, t2 = t & 255;
    float* inq = in_s + q*6048;
    for (int idx = t2; idx < 3*24*84; idx += 256){
      int ic = idx / (24*84); int rem = idx - ic*(24*84);
      int iy = rem / 84, ix = rem - iy*84;
      inq[idx] = cin[((size_t)(b*3+ic)*84 + (q*20 + iy))*84 + ix];
    }
    for (int idx = t; idx < 32*192; idx += 1024) w_s[idx] = c1w[idx];
    if (t < 32) b_s[t] = c1b[t];
    __syncthreads();
    for (int p = t2; p < 800; p += 256){
      int oc = p / 25; int rem = p - oc*25;
      int oy = rem / 5, og = rem - oy*5;
      float a0=b_s[oc],a1=b_s[oc],a2=b_s[oc],a3=b_s[oc];
      #pragma unroll
      for (int ic=0;ic<3;ic++){
        #pragma unroll
        for (int ky=0;ky<8;ky++){
          const float* row = &inq[(ic*24 + oy*4+ky)*84 + og*16];
          float s[20];
          #pragma unroll
          for (int cc=0;cc<20;cc++) s[cc]=row[cc];
          const float* wp = &w_s[(oc*3 + ic)*64 + ky*8];
          #pragma unroll
          for (int kx=0;kx<8;kx++){
            float wv = wp[kx];
            a0 += s[kx]*wv; a1 += s[4+kx]*wv; a2 += s[8+kx]*wv; a3 += s[12+kx]*wv;
          }
        }
      }
      size_t ob = ((size_t)(b*32+oc)*20 + (q*5+oy))*20 + og*4;
      c1o[ob+0]=f2bf(fmaxf(a0,0.f)); c1o[ob+1]=f2bf(fmaxf(a1,0.f));
      c1o[ob+2]=f2bf(fmaxf(a2,0.f)); c1o[ob+3]=f2bf(fmaxf(a3,0.f));
    }
    return;
  }

  // ================= GRU path (exact R9) =================
  unsigned short* obsA = (unsigned short*)smem;
  unsigned char* e8_0 = (unsigned char*)(smem + 2048);
  unsigned char* e8_1 = (unsigned char*)(smem + 10240);
  unsigned char* h8   = (unsigned char*)(smem + 18432);

  obsA[t & 1023] = 0;
  for (int j = t; j < 8192; j += 1024) h8[j] = 0;

  const int w = t >> 6, l = t & 63, lr = l & 15, lh = l >> 4;
  const int jcol = w*16 + lr;
  const float bR  = bih[jcol]     + bhh[jcol];
  const float bZ  = bih[256+jcol] + bhh[256+jcol];
  const float bXN = bih[512+jcol];
  const float bHN = bhh[512+jcol];
  const float bMb = mlpb[jcol];
  const bf16x8 bMLP = *(const bf16x8*)(mlpfrag + w*512 + l*8);

  const unsigned char* wb8 = wfrag8 + w*24576 + l*16;

  const int srow = t >> 2, sk4 = t & 3;
  int rrS = blk*32 + srow; int bS = rrS/24, ndS = 1 + (rrS - bS*24);
  const float* obase4 = obs + (size_t)(bS*25 + ndS)*800 + sk4*4;
  const int obyte = (srow*64 + sk4*8) ^ ((srow&3)<<4);

  const int a8off = lr*256 + lh*8;
  const int xr8 = lr << 3;
  const int o16 = lh*16;
  const int oa0b = (lr*64 + o16) ^ ((lr&3)<<4);
  const int oa1b = ((16+lr)*64 + o16) ^ ((lr&3)<<4);
  const int hw0 = jcol;
  const float S = 1.f/256.f;

  f32x4 hs0 = (f32x4){0.f,0.f,0.f,0.f};
  f32x4 hs1 = (f32x4){0.f,0.f,0.f,0.f};

#define EMB_COMPUTE(DST) { \
  f32x4 e0 = (f32x4){0.f,0.f,0.f,0.f}, e1 = (f32x4){0.f,0.f,0.f,0.f}; \
  bf16x8 oa0 = *(const bf16x8*)((char*)obsA + oa0b); \
  bf16x8 oa1 = *(const bf16x8*)((char*)obsA + oa1b); \
  e0 = MFMA16(oa0, bMLP, e0); \
  e1 = MFMA16(oa1, bMLP, e1); \
  _Pragma("unroll") \
  for (int r=0;r<4;r++){ \
    int m = lh*4 + r; \
    (DST)[(m*256 + hw0) ^ ((m&15)<<3)] = f2fp8(fmaxf(e0[r] + bMb, 0.f)*16.f); \
    int m2 = m + 16; \
    (DST)[(m2*256 + hw0) ^ ((m2&15)<<3)] = f2fp8(fmaxf(e1[r] + bMb, 0.f)*16.f); \
  } }

  __syncthreads();
  if (t < 128){
    float4v ov = *(const float4v*)(obase4);
    uint2v pk;
    pk[0] = (unsigned)f2bf(ov[0]) | ((unsigned)f2bf(ov[1]) << 16);
    pk[1] = (unsigned)f2bf(ov[2]) | ((unsigned)f2bf(ov[3]) << 16);
    *(uint2v*)((char*)obsA + obyte) = pk;
  }
  __syncthreads();
  EMB_COMPUTE(e8_0)
  __syncthreads();

  for (int step=0; step<50; step++){
    const unsigned char* ebuf = (step & 1) ? e8_1 : e8_0;
    unsigned char* nbuf = (step & 1) ? e8_0 : e8_1;
    const bool stg = (t < 128) && (step < 49);
    float4v ov;
    if (stg) ov = *(const float4v*)(obase4 + (size_t)(step+1)*16);

    f32x4 aR0=(f32x4){0,0,0,0}, aR1=(f32x4){0,0,0,0};
    f32x4 aZ0=(f32x4){0,0,0,0}, aZ1=(f32x4){0,0,0,0};
    f32x4 aN0=(f32x4){0,0,0,0}, aN1=(f32x4){0,0,0,0};
    f32x4 aM0=(f32x4){0,0,0,0}, aM1=(f32x4){0,0,0,0};
    __builtin_amdgcn_s_setprio(1);
    #pragma unroll 2
    for (int kkp=0;kkp<4;kkp++){
      const unsigned char* wk8 = wb8 + kkp*6144;
      long2v wIR = *(const long2v*)(wk8);
      long2v wIZ = *(const long2v*)(wk8 + 1024);
      long2v wIN = *(const long2v*)(wk8 + 2048);
      long2v wHR = *(const long2v*)(wk8 + 3072);
      long2v wHZ = *(const long2v*)(wk8 + 4096);
      long2v wHN = *(const long2v*)(wk8 + 5120);
      {
        int kk = kkp*2;
        int ab = a8off + kk*32;
        long eA0 = *(const long*)(ebuf + (ab ^ xr8));
        long eA1 = *(const long*)(ebuf + ((ab + 4096) ^ xr8));
        long hA0 = *(const long*)(h8 + (ab ^ xr8));
        long hA1 = *(const long*)(h8 + ((ab + 4096) ^ xr8));
        aR0 = MFMA8(eA0, wIR[0], aR0);  aR0 = MFMA8(hA0, wHR[0], aR0);
        aR1 = MFMA8(eA1, wIR[0], aR1);  aR1 = MFMA8(hA1, wHR[0], aR1);
        aZ0 = MFMA8(eA0, wIZ[0], aZ0);  aZ0 = MFMA8(hA0, wHZ[0], aZ0);
        aZ1 = MFMA8(eA1, wIZ[0], aZ1);  aZ1 = MFMA8(hA1, wHZ[0], aZ1);
        aN0 = MFMA8(eA0, wIN[0], aN0);  aN1 = MFMA8(eA1, wIN[0], aN1);
        aM0 = MFMA8(hA0, wHN[0], aM0);  aM1 = MFMA8(hA1, wHN[0], aM1);
      }
      {
        int kk = kkp*2 + 1;
        int ab = a8off + kk*32;
        long eA0 = *(const long*)(ebuf + (ab ^ xr8));
        long eA1 = *(const long*)(ebuf + ((ab + 4096) ^ xr8));
        long hA0 = *(const long*)(h8 + (ab ^ xr8));
        long hA1 = *(const long*)(h8 + ((ab + 4096) ^ xr8));
        aR0 = MFMA8(eA0, wIR[1], aR0);  aR0 = MFMA8(hA0, wHR[1], aR0);
        aR1 = MFMA8(eA1, wIR[1], aR1);  aR1 = MFMA8(hA1, wHR[1], aR1);
        aZ0 = MFMA8(eA0, wIZ[1], aZ0);  aZ0 = MFMA8(hA0, wHZ[1], aZ0);
        aZ1 = MFMA8(eA1, wIZ[1], aZ1);  aZ1 = MFMA8(hA1, wHZ[1], aZ1);
        aN0 = MFMA8(eA0, wIN[1], aN0);  aN1 = MFMA8(eA1, wIN[1], aN1);
        aM0 = MFMA8(hA0, wHN[1], aM0);  aM1 = MFMA8(hA1, wHN[1], aM1);
      }
    }
    __builtin_amdgcn_s_setprio(0);
    if (stg){
      uint2v pk;
      pk[0] = (unsigned)f2bf(ov[0]) | ((unsigned)f2bf(ov[1]) << 16);
      pk[1] = (unsigned)f2bf(ov[2]) | ((unsigned)f2bf(ov[3]) << 16);
      *(uint2v*)((char*)obsA + obyte) = pk;
    }
    __syncthreads();
    if (step < 49){
      EMB_COMPUTE(nbuf)
    }
    #pragma unroll
    for (int mt=0;mt<2;mt++){
      f32x4 vR = mt ? aR1 : aR0;
      f32x4 vZ = mt ? aZ1 : aZ0;
      f32x4 vN = mt ? aN1 : aN0;
      f32x4 vM = mt ? aM1 : aM0;
      #pragma unroll
      for (int r=0;r<4;r++){
        float rp = vR[r]*S + bR;
        float zp = vZ[r]*S + bZ;
        float xn = vN[r]*S + bXN;
        float hn = vM[r]*S + bHN;
        float rg = 1.f/(1.f + __expf(-rp));
        float zg = 1.f/(1.f + __expf(-zp));
        float arg = xn + rg*hn;
        float e2 = __expf(2.f*arg);
        float nv = (e2 - 1.f)/(e2 + 1.f);
        float hold = mt ? hs1[r] : hs0[r];
        float hnew = (1.f - zg)*nv + zg*hold;
        if (mt) hs1[r] = hnew; else hs0[r] = hnew;
        int m = mt*16 + lh*4 + r;
        h8[(m*256 + hw0) ^ ((m&15)<<3)] = f2fp8(hnew*16.f);
        if (step == 49){
          int rr = blk*32 + m; int b = rr/24; int nd = 1 + (rr - b*24);
          nemb[(size_t)(b*25+nd)*256 + jcol] = f2bf(hnew);
        }
      }
    }
    __syncthreads();
  }
#undef EMB_COMPUTE
}

// ---------------- GAT scores + softmax + node0 out + dueling head ----------------
__global__ __launch_bounds__(256) void gat_k(const int* __restrict__ edges,
              const unsigned short* __restrict__ glgr,
              const float* __restrict__ att, const float* __restrict__ gbias,
              const float* __restrict__ hidw, const float* __restrict__ hidb,
              const float* __restrict__ outw, const float* __restrict__ outb,
              const float* __restrict__ advw, const float* __restrict__ advb,
              float* __restrict__ out){
  __shared__ int src_s[125], dst_s[125];
  __shared__ __align__(16) float att_s[1280];
  __shared__ float sc[125][5], al[125][5];
  __shared__ float mx[25][5], dn[25][5];
  __shared__ float g0[256], hh[256];
  __shared__ float adv_s[8], v_s;
  __shared__ int e0[125]; __shared__ int ne0;

  int b = blockIdx.x, t = threadIdx.x;
  if (t < 100){ src_s[t] = edges[b*200 + t]; dst_s[t] = edges[b*200 + 100 + t]; }
  else if (t < 125){ src_s[t] = t - 100; dst_s[t] = t - 100; }
  for (int j = t; j < 1280; j += 256) att_s[j] = att[j];
  __syncthreads();
  if (t == 0){ int c = 0; for (int e=0;e<125;e++) if (dst_s[e]==0) e0[c++]=e; ne0 = c; }
  const unsigned short* gbase = glgr + (size_t)b*25*2560;
  for (int p = t; p < 625; p += 256){
    int e = p/5, h = p - 5*(p/5);
    const unsigned short* glp = gbase + src_s[e]*2560 + h*256;
    const unsigned short* grp = gbase + dst_s[e]*2560 + 1280 + h*256;
    const float* ap = &att_s[h*256];
    float acc = 0.f;
    #pragma unroll 4
    for (int c=0;c<256;c+=8){
      uint4v gu = *(const uint4v*)&glp[c];
      uint4v ru = *(const uint4v*)&grp[c];
      #pragma unroll
      for (int q=0;q<4;q++){
        float s0 = bflo(gu[q]) + bflo(ru[q]);
        float s1 = bfhi(gu[q]) + bfhi(ru[q]);
        s0 = (s0 > 0.f) ? s0 : 0.2f*s0;
        s1 = (s1 > 0.f) ? s1 : 0.2f*s1;
        acc += s0*ap[c+2*q] + s1*ap[c+2*q+1];
      }
    }
    sc[e][h] = acc;
  }
  __syncthreads();
  if (t < 125){
    int j = t/5, h = t - 5*(t/5);
    float m = -1e30f;
    for (int e=0;e<125;e++) if (dst_s[e]==j) m = fmaxf(m, sc[e][h]);
    float d = 0.f;
    for (int e=0;e<125;e++) if (dst_s[e]==j) d += __expf(sc[e][h]-m);
    mx[j][h] = m; dn[j][h] = d;
  }
  __syncthreads();
  for (int p = t; p < 625; p += 256){
    int e = p/5, h = p - 5*(p/5);
    int dd = dst_s[e];
    al[e][h] = __expf(sc[e][h] - mx[dd][h]) / dn[dd][h];
  }
  __syncthreads();
  if (t < 101){
    out[2048 + b*101 + t] = (al[t][0]+al[t][1]+al[t][2]+al[t][3]+al[t][4])*0.2f;
  }
  {
    float acc = 0.f;
    for (int x=0;x<ne0;x++){
      int e = e0[x]; int s = src_s[e];
      const unsigned short* glp = gbase + s*2560 + t;
      #pragma unroll
      for (int h=0;h<5;h++) acc += al[e][h]*bf2f(glp[h*256]);
    }
    g0[t] = acc*0.2f + gbias[t];
  }
  __syncthreads();
  {
    float acc = hidb[t];
    for (int k=0;k<256;k++) acc += g0[k]*hidw[k*256+t];
    hh[t] = fmaxf(acc, 0.f);
  }
  __syncthreads();
  if (t < 8){
    float acc = advb[t];
    for (int k=0;k<256;k++) acc += hh[k]*advw[k*8+t];
    adv_s[t] = acc;
  } else if (t == 8){
    float acc = outb[0];
    for (int k=0;k<256;k++) acc += hh[k]*outw[k];
    v_s = acc;
  }
  __syncthreads();
  if (t < 8){
    float m = adv_s[0]+adv_s[1]+adv_s[2]+adv_s[3]+adv_s[4]+adv_s[5]+adv_s[6]+adv_s[7];
    out[b*8+t] = v_s + adv_s[t] - m*0.125f;
  }
}

extern "C" void kernel_launch(void* const* d_in, const int* in_sizes, int n_in,
                              void* d_out, int out_size, void* d_ws, size_t ws_size,
                              hipStream_t stream){
  const float* obs     = (const float*)d_in[0];
  const float* obs_map = (const float*)d_in[1];
  const int*   edges   = (const int*)d_in[2];
  const float* mlp_w = (const float*)d_in[4];
  const float* mlp_b = (const float*)d_in[5];
  const float* c1w = (const float*)d_in[6];  const float* c1b = (const float*)d_in[7];
  const float* c2w = (const float*)d_in[8];  const float* c2b = (const float*)d_in[9];
  const float* c3w = (const float*)d_in[10]; const float* c3b = (const float*)d_in[11];
  const float* fcw = (const float*)d_in[12]; const float* fcb = (const float*)d_in[13];
  const float* wih = (const float*)d_in[14]; const float* whh = (const float*)d_in[15];
  const float* bih = (const float*)d_in[16]; const float* bhh = (const float*)d_in[17];
  const float* gwl = (const float*)d_in[18]; const float* gbl = (const float*)d_in[19];
  const float* gwr = (const float*)d_in[20]; const float* gbr = (const float*)d_in[21];
  const float* gatt = (const float*)d_in[22]; const float* gbias = (const float*)d_in[23];
  const float* hidw = (const float*)d_in[24]; const float* hidb = (const float*)d_in[25];
  const float* outw = (const float*)d_in[26]; const float* outb = (const float*)d_in[27];
  const float* advw = (const float*)d_in[28]; const float* advb = (const float*)d_in[29];
  float* out = (float*)d_out;
  char* ws = (char*)d_ws;

  // workspace layout (c1o/c3o/fcpart aliased under glgr; consumed before glgr write)
  unsigned short* c1o  = (unsigned short*)(ws + 0);          // 6,553,600 B
  unsigned short* c3o  = (unsigned short*)(ws + 6553600);    // 1,605,632 B
  float*          fcpart = (float*)(ws + 16000000);          // 1,835,008 B
  unsigned short* glgr = (unsigned short*)(ws + 0);          // 32,768,000 B
  size_t o = 32768000;
  unsigned short* nemb    = (unsigned short*)(ws + o); o += 3276800;
  unsigned char*  wfrag8  = (unsigned char*)(ws + o);  o += 393216;
  unsigned short* mlpfrag = (unsigned short*)(ws + o); o += 16384;
  unsigned short* wlrT    = (unsigned short*)(ws + o); o += 1310720;
  unsigned short* fcwT    = (unsigned short*)(ws + o); o += 1605632;
  float* blbr             = (float*)(ws + o); o += 10240;
  unsigned short* c2wb    = (unsigned short*)(ws + o); o += 65536;
  unsigned short* c3wb    = (unsigned short*)(ws + o); o += 73728;

  prep_k<<<1850, 256, 0, stream>>>(wih, whh, gbl, gbr, mlp_w, c2w, c3w,
                                   wfrag8, mlpfrag, blbr, c2wb, c3wb);
  tr_fc_k<<<196, 256, 0, stream>>>(fcw, fcwT);
  tr_wlr_k<<<160, 256, 0, stream>>>(gwl, gwr, wlrT);
  gruconv_k<<<448, 1024, 0, stream>>>(obs, wfrag8, mlpfrag, mlp_b, bih, bhh, nemb,
                                      obs_map, c1w, c1b, c1o);                    // gru + conv1
  conv23_k<<<256, 1024, 0, stream>>>(c1o, c2wb, c2b, c3wb, c3b, c3o);
  gemm_fc_k<<<112, 256, 0, stream>>>(c3o, fcwT, fcpart);                          // FC split-K
  fc_red_k<<<256, 256, 0, stream>>>(fcpart, fcb, nemb);                           // -> node 0
  gemm_k<<<4000, 256, 0, stream>>>(nemb, wlrT, blbr, glgr, 256, 2560, 1, 0, 40);  // gl|gr
  gat_k<<<256, 256, 0, stream>>>(edges, glgr, gatt, gbias, hidw, hidb, outw, outb, advw, advb, out);
}

// Round 15
// 730.690 us; speedup vs baseline: 3.1747x; 1.0273x over previous
//
#include <hip/hip_runtime.h>
#include <cstdint>

typedef __attribute__((ext_vector_type(8))) __bf16 bf16x8;
typedef __attribute__((ext_vector_type(4))) float f32x4;
typedef __attribute__((ext_vector_type(4))) unsigned int uint4v;
typedef __attribute__((ext_vector_type(2))) unsigned int uint2v;
typedef __attribute__((ext_vector_type(4))) float float4v;
typedef __attribute__((ext_vector_type(2))) long long2v;

__device__ __forceinline__ unsigned short f2bf(float x){
  union { float f; unsigned u; } v; v.f = x;
  unsigned r = v.u + 0x7FFFu + ((v.u >> 16) & 1u);
  return (unsigned short)(r >> 16);
}
__device__ __forceinline__ float bf2f(unsigned short h){
  union { unsigned u; float f; } v; v.u = ((unsigned)h) << 16;
  return v.f;
}
__device__ __forceinline__ float bflo(unsigned u){
  union { unsigned x; float f; } v; v.x = u << 16; return v.f;
}
__device__ __forceinline__ float bfhi(unsigned u){
  union { unsigned x; float f; } v; v.x = u & 0xFFFF0000u; return v.f;
}
__device__ __forceinline__ f32x4 MFMA16(bf16x8 a, bf16x8 b, f32x4 c){
  return __builtin_amdgcn_mfma_f32_16x16x32_bf16(a, b, c, 0, 0, 0);
}
__device__ __forceinline__ f32x4 MFMA8(long a, long b, f32x4 c){
  return __builtin_amdgcn_mfma_f32_16x16x32_fp8_fp8(a, b, c, 0, 0, 0);
}
__device__ __forceinline__ unsigned char f2fp8(float x){
  int p = __builtin_amdgcn_cvt_pk_fp8_f32(x, x, 0, false);
  return (unsigned char)(p & 0xFF);
}

// ---------------- prep (merged: conversions + both LDS-tiled transposes) ----------
// blocks [0,1850): elementwise prep; [1850,2046): fcw transpose; [2046,2206): wl/wr T
__global__ __launch_bounds__(256) void prep_k(
    const float* __restrict__ wih, const float* __restrict__ whh,
    const float* __restrict__ bl, const float* __restrict__ br,
    const float* __restrict__ mlpw,
    const float* __restrict__ c2w, const float* __restrict__ c3w,
    const float* __restrict__ fcw, const float* __restrict__ wl, const float* __restrict__ wr,
    unsigned char* __restrict__ wfrag8, unsigned short* __restrict__ mlpfrag,
    float* __restrict__ blbr,
    unsigned short* __restrict__ c2wb, unsigned short* __restrict__ c3wb,
    unsigned short* __restrict__ fcwT, unsigned short* __restrict__ wlrT){
  __shared__ float tile[64][65];
  int bid = blockIdx.x, t = threadIdx.x;
  if (bid < 1850){
    int i = bid*256 + t;
    if (i < 393216){
      int b16 = i & 15;
      int l   = (i >> 4) & 63;
      int chunk = i >> 10;           // (w*4+kkp)*6+mg
      int wkp = chunk / 6;
      int mg  = chunk - 6*wkp;
      int w = wkp >> 2, kkp = wkp & 3;
      int ks = b16 >> 3, e = b16 & 7;
      int kk = kkp*2 + ks;
      int mat = mg / 3, g = mg - 3*(mg/3);
      int n = g*256 + w*16 + (l & 15);
      int k = kk*32 + (l >> 4)*8 + e;
      float v = 16.f * (mat ? whh[n*256 + k] : wih[n*256 + k]);
      wfrag8[i] = f2fp8(v);
      return;
    }
    i -= 393216;
    if (i < 8192){
      int w = i >> 9;
      int r4 = i & 511;
      int l = r4 >> 3, e = r4 & 7;
      int n = w*16 + (l & 15);
      int k = (l >> 4)*8 + e;
      mlpfrag[i] = (k < 16) ? f2bf(mlpw[k*256 + n]) : (unsigned short)0;
      return;
    }
    i -= 8192;
    if (i < 2560){
      blbr[i] = (i < 1280) ? bl[i] : br[i-1280];
      return;
    }
    i -= 2560;
    if (i < 32768){ c2wb[i] = f2bf(c2w[i]); return; }
    i -= 32768;
    if (i < 36864){ c3wb[i] = f2bf(c3w[i]); }
    return;
  }
  if (bid < 2046){
    int tb = bid - 1850;
    int ti = tb >> 2, tj = tb & 3;
    for (int idx = t; idx < 4096; idx += 256){
      int r = idx >> 6, c = idx & 63;
      tile[r][c] = fcw[(size_t)(ti*64 + r)*256 + tj*64 + c];
    }
    __syncthreads();
    for (int idx = t; idx < 4096; idx += 256){
      int r = idx >> 6, c = idx & 63;
      fcwT[(size_t)(tj*64 + r)*3136 + ti*64 + c] = f2bf(tile[c][r]);
    }
    return;
  }
  {
    int tb = bid - 2046;
    int m = tb / 80; int rem = tb - m*80;
    int tk = rem / 20, tn = rem - tk*20;
    const float* src = m ? wr : wl;
    for (int idx = t; idx < 4096; idx += 256){
      int r = idx >> 6, c = idx & 63;
      tile[r][c] = src[(size_t)(tk*64 + r)*1280 + tn*64 + c];
    }
    __syncthreads();
    for (int idx = t; idx < 4096; idx += 256){
      int r = idx >> 6, c = idx & 63;
      wlrT[(size_t)(m*1280 + tn*64 + r)*256 + tk*64 + c] = f2bf(tile[c][r]);
    }
  }
}

// ---------------- conv23: fused conv2+conv3 per batch, LDS intermediates ----------
__global__ __launch_bounds__(1024) void conv23_k(const unsigned short* __restrict__ c1o,
              const unsigned short* __restrict__ c2wb, const float* __restrict__ c2b,
              const unsigned short* __restrict__ c3wb, const float* __restrict__ c3b,
              unsigned short* __restrict__ c3o){
  __shared__ __align__(16) char cs[102016];
  unsigned short* in_s = (unsigned short*)cs;            // [32][20][20] = 25600 B
  unsigned short* w2s  = (unsigned short*)(cs + 25600);  // 65536 B
  float* b2            = (float*)(cs + 91136);           // 256 B
  unsigned short* c2s  = (unsigned short*)(cs + 91392);  // [64][9][9] = 10368 B
  unsigned short* w3s  = (unsigned short*)cs;            // 73728 B (overlay, phase B)
  float* b3            = (float*)(cs + 101760);          // 256 B
  int b = blockIdx.x, t = threadIdx.x;
  int q = t >> 8, t2 = t & 255;
  for (int idx = t; idx < 12800; idx += 1024) in_s[idx] = c1o[(size_t)b*12800 + idx];
  for (int idx = t; idx < 32768; idx += 1024) w2s[idx] = c2wb[idx];
  if (t < 64) b2[t] = c2b[t];
  if (t >= 64 && t < 128) b3[t-64] = c3b[t-64];
  __syncthreads();
  for (int p = t2; p < 432; p += 256){
    int ocl = p / 27; int rem = p - ocl*27;
    int oy = rem / 3, og = rem - oy*3;
    int oc = q*16 + ocl;
    float a0=b2[oc],a1=b2[oc],a2=b2[oc];
    #pragma unroll 4
    for (int ic=0;ic<32;ic++){
      #pragma unroll
      for (int ky=0;ky<4;ky++){
        const unsigned short* row = &in_s[(ic*20 + oy*2+ky)*20 + og*6];
        float s[8];
        #pragma unroll
        for (int cc=0;cc<8;cc++) s[cc]=bf2f(row[cc]);
        const unsigned short* wp = &w2s[((oc*32+ic)*4+ky)*4];
        #pragma unroll
        for (int kx=0;kx<4;kx++){
          float wv = bf2f(wp[kx]);
          a0 += s[kx]*wv; a1 += s[2+kx]*wv; a2 += s[4+kx]*wv;
        }
      }
    }
    int ob = (oc*9 + oy)*9 + og*3;
    c2s[ob+0]=f2bf(fmaxf(a0,0.f)); c2s[ob+1]=f2bf(fmaxf(a1,0.f)); c2s[ob+2]=f2bf(fmaxf(a2,0.f));
  }
  __syncthreads();
  for (int idx = t; idx < 36864; idx += 1024) w3s[idx] = c3wb[idx];
  __syncthreads();
  for (int p = t2; p < 224; p += 256){
    int ocl = p / 14; int rem = p - ocl*14;
    int oy = rem >> 1, og = rem & 1;
    int ox0 = og*4; int nx = og ? 3 : 4;
    int oc = q*16 + ocl;
    float a[4]; a[0]=a[1]=a[2]=a[3]=b3[oc];
    for (int ic=0;ic<64;ic++){
      #pragma unroll
      for (int ky=0;ky<3;ky++){
        const unsigned short* row = &c2s[(ic*9 + oy+ky)*9 + ox0];
        float s[6];
        #pragma unroll
        for (int cc=0;cc<6;cc++) s[cc] = (ox0+cc < 9) ? bf2f(row[cc]) : 0.f;
        const unsigned short* wp = &w3s[((oc*64+ic)*3+ky)*3];
        #pragma unroll
        for (int kx=0;kx<3;kx++){
          float wv = bf2f(wp[kx]);
          #pragma unroll
          for (int jj=0;jj<4;jj++) a[jj] += s[jj+kx]*wv;
        }
      }
    }
    size_t ob = (size_t)b*3136 + oc*49 + oy*7 + ox0;
    #pragma unroll
    for (int jj=0;jj<4;jj++) if (jj < nx) c3o[ob+jj] = f2bf(fmaxf(a[jj],0.f));
  }
}

// ---------------- generic MFMA GEMM: C[m,n] = act(A[m,:]·B[n,:] + bias[n]) ----
__global__ __launch_bounds__(256) void gemm_k(const unsigned short* __restrict__ A,
              const unsigned short* __restrict__ B, const float* __restrict__ bias,
              unsigned short* __restrict__ C, int K, int ldc, int rowmul, int relu, int Nblk){
  __shared__ __align__(16) unsigned short As[64*32];
  __shared__ __align__(16) unsigned short Bs[64*32];
  int bid = blockIdx.x;
  int nb = bid % Nblk, mb = bid / Nblk;
  int t = threadIdx.x;
  int w = t >> 6, l = t & 63, lr = l & 15, lh = l >> 4;
  int sr = t >> 2, sq = t & 3;
  f32x4 acc[4];
  #pragma unroll
  for (int i=0;i<4;i++) acc[i] = (f32x4){0.f,0.f,0.f,0.f};
  int nkk = K >> 5;
  const size_t a_row = (size_t)(mb*64 + sr)*K;
  const size_t b_row = (size_t)(nb*64 + sr)*K;
  for (int kk=0;kk<nkk;kk++){
    uint4v av = *(const uint4v*)&A[a_row + kk*32 + sq*8];
    uint4v bv = *(const uint4v*)&B[b_row + kk*32 + sq*8];
    __syncthreads();
    *(uint4v*)((char*)As + ((sr*64 + sq*16) ^ ((sr&3)<<4))) = av;
    *(uint4v*)((char*)Bs + ((sr*64 + sq*16) ^ ((sr&3)<<4))) = bv;
    __syncthreads();
    int brow = w*16 + lr;
    bf16x8 bfr = *(const bf16x8*)((char*)Bs + ((brow*64 + lh*16) ^ ((brow&3)<<4)));
    #pragma unroll
    for (int mt=0;mt<4;mt++){
      int arow = mt*16 + lr;
      bf16x8 afr = *(const bf16x8*)((char*)As + ((arow*64 + lh*16) ^ ((arow&3)<<4)));
      acc[mt] = MFMA16(afr, bfr, acc[mt]);
    }
  }
  int col = nb*64 + w*16 + lr;
  float bn = bias[col];
  #pragma unroll
  for (int mt=0;mt<4;mt++){
    #pragma unroll
    for (int r=0;r<4;r++){
      int row = mb*64 + mt*16 + lh*4 + r;
      float v = acc[mt][r] + bn;
      if (relu) v = fmaxf(v, 0.f);
      C[(size_t)row*rowmul*ldc + col] = f2bf(v);
    }
  }
}

// ---------------- FC split-K GEMM: 112 blocks = 16 tiles x 7 K-slices, f32 partials ----
__global__ __launch_bounds__(256) void gemm_fc_k(const unsigned short* __restrict__ A,
              const unsigned short* __restrict__ B, float* __restrict__ P){
  __shared__ __align__(16) unsigned short As[64*32];
  __shared__ __align__(16) unsigned short Bs[64*32];
  int bid = blockIdx.x;
  int s = bid % 7, tile = bid / 7;
  int nb = tile & 3, mb = tile >> 2;
  int t = threadIdx.x;
  int w = t >> 6, l = t & 63, lr = l & 15, lh = l >> 4;
  int sr = t >> 2, sq = t & 3;
  f32x4 acc[4];
  #pragma unroll
  for (int i=0;i<4;i++) acc[i] = (f32x4){0.f,0.f,0.f,0.f};
  const int K = 3136;
  const size_t a_row = (size_t)(mb*64 + sr)*K;
  const size_t b_row = (size_t)(nb*64 + sr)*K;
  for (int kk = s*14; kk < s*14 + 14; kk++){
    uint4v av = *(const uint4v*)&A[a_row + kk*32 + sq*8];
    uint4v bv = *(const uint4v*)&B[b_row + kk*32 + sq*8];
    __syncthreads();
    *(uint4v*)((char*)As + ((sr*64 + sq*16) ^ ((sr&3)<<4))) = av;
    *(uint4v*)((char*)Bs + ((sr*64 + sq*16) ^ ((sr&3)<<4))) = bv;
    __syncthreads();
    int brow = w*16 + lr;
    bf16x8 bfr = *(const bf16x8*)((char*)Bs + ((brow*64 + lh*16) ^ ((brow&3)<<4)));
    #pragma unroll
    for (int mt=0;mt<4;mt++){
      int arow = mt*16 + lr;
      bf16x8 afr = *(const bf16x8*)((char*)As + ((arow*64 + lh*16) ^ ((arow&3)<<4)));
      acc[mt] = MFMA16(afr, bfr, acc[mt]);
    }
  }
  int col = nb*64 + w*16 + lr;
  #pragma unroll
  for (int mt=0;mt<4;mt++){
    #pragma unroll
    for (int r=0;r<4;r++){
      int row = mb*64 + mt*16 + lh*4 + r;
      P[(size_t)s*65536 + row*256 + col] = acc[mt][r];
    }
  }
}

// ---------------- FC reduce: sum 7 partials + bias + relu -> nemb node-0 rows ----
__global__ __launch_bounds__(256) void fc_red_k(const float* __restrict__ P,
              const float* __restrict__ fcb, unsigned short* __restrict__ nemb){
  int idx = blockIdx.x*256 + threadIdx.x;       // 65536 total
  int row = idx >> 8, col = idx & 255;
  float sum = fcb[col];
  #pragma unroll
  for (int k=0;k<7;k++) sum += P[k*65536 + idx];
  nemb[(size_t)row*25*256 + col] = f2bf(fmaxf(sum, 0.f));
}

// ---------------- mega kernel: blocks 0..191 = GRU (R9); 192..447 = conv1 (R11) --------
__global__ __launch_bounds__(1024, 4)
void gruconv_k(const float* __restrict__ obs,
              const unsigned char* __restrict__ wfrag8,
              const unsigned short* __restrict__ mlpfrag,
              const float* __restrict__ mlpb,
              const float* __restrict__ bih, const float* __restrict__ bhh,
              unsigned short* __restrict__ nemb,
              const float* __restrict__ cin, const float* __restrict__ c1w,
              const float* __restrict__ c1b, unsigned short* __restrict__ c1o){
  __shared__ __align__(16) char smem[121984];

  const int t = threadIdx.x, blk = blockIdx.x;

  if (blk >= 192){
    // ================= conv1 path =================
    float* in_s = (float*)smem;                     // [4][3][24][84] = 96768 B
    float* w_s  = (float*)(smem + 96768);           // [32][3][8][8]  = 24576 B
    float* b_s  = (float*)(smem + 121344);          // [32]
    int b = blk - 192;
    int q = t >> 8, t2 = t & 255;
    float* inq = in_s + q*6048;
    for (int idx = t2; idx < 3*24*84; idx += 256){
      int ic = idx / (24*84); int rem = idx - ic*(24*84);
      int iy = rem / 84, ix = rem - iy*84;
      inq[idx] = cin[((size_t)(b*3+ic)*84 + (q*20 + iy))*84 + ix];
    }
    for (int idx = t; idx < 32*192; idx += 1024) w_s[idx] = c1w[idx];
    if (t < 32) b_s[t] = c1b[t];
    __syncthreads();
    for (int p = t2; p < 800; p += 256){
      int oc = p / 25; int rem = p - oc*25;
      int oy = rem / 5, og = rem - oy*5;
      float a0=b_s[oc],a1=b_s[oc],a2=b_s[oc],a3=b_s[oc];
      #pragma unroll
      for (int ic=0;ic<3;ic++){
        #pragma unroll
        for (int ky=0;ky<8;ky++){
          const float* row = &inq[(ic*24 + oy*4+ky)*84 + og*16];
          float s[20];
          #pragma unroll
          for (int cc=0;cc<20;cc++) s[cc]=row[cc];
          const float* wp = &w_s[(oc*3 + ic)*64 + ky*8];
          #pragma unroll
          for (int kx=0;kx<8;kx++){
            float wv = wp[kx];
            a0 += s[kx]*wv; a1 += s[4+kx]*wv; a2 += s[8+kx]*wv; a3 += s[12+kx]*wv;
          }
        }
      }
      size_t ob = ((size_t)(b*32+oc)*20 + (q*5+oy))*20 + og*4;
      c1o[ob+0]=f2bf(fmaxf(a0,0.f)); c1o[ob+1]=f2bf(fmaxf(a1,0.f));
      c1o[ob+2]=f2bf(fmaxf(a2,0.f)); c1o[ob+3]=f2bf(fmaxf(a3,0.f));
    }
    return;
  }

  // ================= GRU path (exact R9) =================
  unsigned short* obsA = (unsigned short*)smem;
  unsigned char* e8_0 = (unsigned char*)(smem + 2048);
  unsigned char* e8_1 = (unsigned char*)(smem + 10240);
  unsigned char* h8   = (unsigned char*)(smem + 18432);

  obsA[t & 1023] = 0;
  for (int j = t; j < 8192; j += 1024) h8[j] = 0;

  const int w = t >> 6, l = t & 63, lr = l & 15, lh = l >> 4;
  const int jcol = w*16 + lr;
  const float bR  = bih[jcol]     + bhh[jcol];
  const float bZ  = bih[256+jcol] + bhh[256+jcol];
  const float bXN = bih[512+jcol];
  const float bHN = bhh[512+jcol];
  const float bMb = mlpb[jcol];
  const bf16x8 bMLP = *(const bf16x8*)(mlpfrag + w*512 + l*8);

  const unsigned char* wb8 = wfrag8 + w*24576 + l*16;

  const int srow = t >> 2, sk4 = t & 3;
  int rrS = blk*32 + srow; int bS = rrS/24, ndS = 1 + (rrS - bS*24);
  const float* obase4 = obs + (size_t)(bS*25 + ndS)*800 + sk4*4;
  const int obyte = (srow*64 + sk4*8) ^ ((srow&3)<<4);

  const int a8off = lr*256 + lh*8;
  const int xr8 = lr << 3;
  const int o16 = lh*16;
  const int oa0b = (lr*64 + o16) ^ ((lr&3)<<4);
  const int oa1b = ((16+lr)*64 + o16) ^ ((lr&3)<<4);
  const int hw0 = jcol;
  const float S = 1.f/256.f;

  f32x4 hs0 = (f32x4){0.f,0.f,0.f,0.f};
  f32x4 hs1 = (f32x4){0.f,0.f,0.f,0.f};

#define EMB_COMPUTE(DST) { \
  f32x4 e0 = (f32x4){0.f,0.f,0.f,0.f}, e1 = (f32x4){0.f,0.f,0.f,0.f}; \
  bf16x8 oa0 = *(const bf16x8*)((char*)obsA + oa0b); \
  bf16x8 oa1 = *(const bf16x8*)((char*)obsA + oa1b); \
  e0 = MFMA16(oa0, bMLP, e0); \
  e1 = MFMA16(oa1, bMLP, e1); \
  _Pragma("unroll") \
  for (int r=0;r<4;r++){ \
    int m = lh*4 + r; \
    (DST)[(m*256 + hw0) ^ ((m&15)<<3)] = f2fp8(fmaxf(e0[r] + bMb, 0.f)*16.f); \
    int m2 = m + 16; \
    (DST)[(m2*256 + hw0) ^ ((m2&15)<<3)] = f2fp8(fmaxf(e1[r] + bMb, 0.f)*16.f); \
  } }

  __syncthreads();
  if (t < 128){
    float4v ov = *(const float4v*)(obase4);
    uint2v pk;
    pk[0] = (unsigned)f2bf(ov[0]) | ((unsigned)f2bf(ov[1]) << 16);
    pk[1] = (unsigned)f2bf(ov[2]) | ((unsigned)f2bf(ov[3]) << 16);
    *(uint2v*)((char*)obsA + obyte) = pk;
  }
  __syncthreads();
  EMB_COMPUTE(e8_0)
  __syncthreads();

  for (int step=0; step<50; step++){
    const unsigned char* ebuf = (step & 1) ? e8_1 : e8_0;
    unsigned char* nbuf = (step & 1) ? e8_0 : e8_1;
    const bool stg = (t < 128) && (step < 49);
    float4v ov;
    if (stg) ov = *(const float4v*)(obase4 + (size_t)(step+1)*16);

    f32x4 aR0=(f32x4){0,0,0,0}, aR1=(f32x4){0,0,0,0};
    f32x4 aZ0=(f32x4){0,0,0,0}, aZ1=(f32x4){0,0,0,0};
    f32x4 aN0=(f32x4){0,0,0,0}, aN1=(f32x4){0,0,0,0};
    f32x4 aM0=(f32x4){0,0,0,0}, aM1=(f32x4){0,0,0,0};
    __builtin_amdgcn_s_setprio(1);
    #pragma unroll 2
    for (int kkp=0;kkp<4;kkp++){
      const unsigned char* wk8 = wb8 + kkp*6144;
      long2v wIR = *(const long2v*)(wk8);
      long2v wIZ = *(const long2v*)(wk8 + 1024);
      long2v wIN = *(const long2v*)(wk8 + 2048);
      long2v wHR = *(const long2v*)(wk8 + 3072);
      long2v wHZ = *(const long2v*)(wk8 + 4096);
      long2v wHN = *(const long2v*)(wk8 + 5120);
      {
        int kk = kkp*2;
        int ab = a8off + kk*32;
        long eA0 = *(const long*)(ebuf + (ab ^ xr8));
        long eA1 = *(const long*)(ebuf + ((ab + 4096) ^ xr8));
        long hA0 = *(const long*)(h8 + (ab ^ xr8));
        long hA1 = *(const long*)(h8 + ((ab + 4096) ^ xr8));
        aR0 = MFMA8(eA0, wIR[0], aR0);  aR0 = MFMA8(hA0, wHR[0], aR0);
        aR1 = MFMA8(eA1, wIR[0], aR1);  aR1 = MFMA8(hA1, wHR[0], aR1);
        aZ0 = MFMA8(eA0, wIZ[0], aZ0);  aZ0 = MFMA8(hA0, wHZ[0], aZ0);
        aZ1 = MFMA8(eA1, wIZ[0], aZ1);  aZ1 = MFMA8(hA1, wHZ[0], aZ1);
        aN0 = MFMA8(eA0, wIN[0], aN0);  aN1 = MFMA8(eA1, wIN[0], aN1);
        aM0 = MFMA8(hA0, wHN[0], aM0);  aM1 = MFMA8(hA1, wHN[0], aM1);
      }
      {
        int kk = kkp*2 + 1;
        int ab = a8off + kk*32;
        long eA0 = *(const long*)(ebuf + (ab ^ xr8));
        long eA1 = *(const long*)(ebuf + ((ab + 4096) ^ xr8));
        long hA0 = *(const long*)(h8 + (ab ^ xr8));
        long hA1 = *(const long*)(h8 + ((ab + 4096) ^ xr8));
        aR0 = MFMA8(eA0, wIR[1], aR0);  aR0 = MFMA8(hA0, wHR[1], aR0);
        aR1 = MFMA8(eA1, wIR[1], aR1);  aR1 = MFMA8(hA1, wHR[1], aR1);
        aZ0 = MFMA8(eA0, wIZ[1], aZ0);  aZ0 = MFMA8(hA0, wHZ[1], aZ0);
        aZ1 = MFMA8(eA1, wIZ[1], aZ1);  aZ1 = MFMA8(hA1, wHZ[1], aZ1);
        aN0 = MFMA8(eA0, wIN[1], aN0);  aN1 = MFMA8(eA1, wIN[1], aN1);
        aM0 = MFMA8(hA0, wHN[1], aM0);  aM1 = MFMA8(hA1, wHN[1], aM1);
      }
    }
    __builtin_amdgcn_s_setprio(0);
    if (stg){
      uint2v pk;
      pk[0] = (unsigned)f2bf(ov[0]) | ((unsigned)f2bf(ov[1]) << 16);
      pk[1] = (unsigned)f2bf(ov[2]) | ((unsigned)f2bf(ov[3]) << 16);
      *(uint2v*)((char*)obsA + obyte) = pk;
    }
    __syncthreads();
    if (step < 49){
      EMB_COMPUTE(nbuf)
    }
    #pragma unroll
    for (int mt=0;mt<2;mt++){
      f32x4 vR = mt ? aR1 : aR0;
      f32x4 vZ = mt ? aZ1 : aZ0;
      f32x4 vN = mt ? aN1 : aN0;
      f32x4 vM = mt ? aM1 : aM0;
      #pragma unroll
      for (int r=0;r<4;r++){
        float rp = vR[r]*S + bR;
        float zp = vZ[r]*S + bZ;
        float xn = vN[r]*S + bXN;
        float hn = vM[r]*S + bHN;
        float rg = 1.f/(1.f + __expf(-rp));
        float zg = 1.f/(1.f + __expf(-zp));
        float arg = xn + rg*hn;
        float e2 = __expf(2.f*arg);
        float nv = (e2 - 1.f)/(e2 + 1.f);
        float hold = mt ? hs1[r] : hs0[r];
        float hnew = (1.f - zg)*nv + zg*hold;
        if (mt) hs1[r] = hnew; else hs0[r] = hnew;
        int m = mt*16 + lh*4 + r;
        h8[(m*256 + hw0) ^ ((m&15)<<3)] = f2fp8(hnew*16.f);
        if (step == 49){
          int rr = blk*32 + m; int b = rr/24; int nd = 1 + (rr - b*24);
          nemb[(size_t)(b*25+nd)*256 + jcol] = f2bf(hnew);
        }
      }
    }
    __syncthreads();
  }
#undef EMB_COMPUTE
}

// ---------------- GAT v2: 1024 threads/graph, fully parallel scores + split-K GEMMs ----
__global__ __launch_bounds__(1024) void gat_k(const int* __restrict__ edges,
              const unsigned short* __restrict__ glgr,
              const float* __restrict__ att, const float* __restrict__ gbias,
              const float* __restrict__ hidw, const float* __restrict__ hidb,
              const float* __restrict__ outw, const float* __restrict__ outb,
              const float* __restrict__ advw, const float* __restrict__ advb,
              float* __restrict__ out){
  __shared__ int src_s[125], dst_s[125];
  __shared__ __align__(16) float att_s[1280];
  __shared__ float sc[125][5], al[125][5];
  __shared__ float mx[25][5], dn[25][5];
  __shared__ float g0p[4][256];
  __shared__ float hp[4][256];
  __shared__ float g0[256], hh[256];
  __shared__ float adv_s[8], v_s;
  __shared__ int e0[125]; __shared__ int ne0;

  int b = blockIdx.x, t = threadIdx.x;
  int qq = t >> 8, t2 = t & 255;
  if (t < 100){ src_s[t] = edges[b*200 + t]; dst_s[t] = edges[b*200 + 100 + t]; }
  else if (t < 125){ src_s[t] = t - 100; dst_s[t] = t - 100; }
  for (int j = t; j < 1280; j += 1024) att_s[j] = att[j];
  __syncthreads();
  if (t == 0){ int c = 0; for (int e=0;e<125;e++) if (dst_s[e]==0) e0[c++]=e; ne0 = c; }
  const unsigned short* gbase = glgr + (size_t)b*25*2560;
  if (t < 625){
    int e = t/5, h = t - 5*(t/5);
    const unsigned short* glp = gbase + src_s[e]*2560 + h*256;
    const unsigned short* grp = gbase + dst_s[e]*2560 + 1280 + h*256;
    const float* ap = &att_s[h*256];
    float acc = 0.f;
    #pragma unroll 4
    for (int c=0;c<256;c+=8){
      uint4v gu = *(const uint4v*)&glp[c];
      uint4v ru = *(const uint4v*)&grp[c];
      #pragma unroll
      for (int q=0;q<4;q++){
        float s0 = bflo(gu[q]) + bflo(ru[q]);
        float s1 = bfhi(gu[q]) + bfhi(ru[q]);
        s0 = (s0 > 0.f) ? s0 : 0.2f*s0;
        s1 = (s1 > 0.f) ? s1 : 0.2f*s1;
        acc += s0*ap[c+2*q] + s1*ap[c+2*q+1];
      }
    }
    sc[e][h] = acc;
  }
  __syncthreads();
  if (t < 125){
    int j = t/5, h = t - 5*(t/5);
    float m = -1e30f;
    for (int e=0;e<125;e++) if (dst_s[e]==j) m = fmaxf(m, sc[e][h]);
    float d = 0.f;
    for (int e=0;e<125;e++) if (dst_s[e]==j) d += __expf(sc[e][h]-m);
    mx[j][h] = m; dn[j][h] = d;
  }
  __syncthreads();
  if (t < 625){
    int e = t/5, h = t - 5*(t/5);
    int dd = dst_s[e];
    al[e][h] = __expf(sc[e][h] - mx[dd][h]) / dn[dd][h];
  }
  __syncthreads();
  if (t < 101){
    out[2048 + b*101 + t] = (al[t][0]+al[t][1]+al[t][2]+al[t][3]+al[t][4])*0.2f;
  }
  // g0 partials: thread (qq,t2) sums e0 entries x = qq, qq+4, ...
  {
    float acc = 0.f;
    for (int x=qq; x<ne0; x+=4){
      int e = e0[x]; int s = src_s[e];
      const unsigned short* glp = gbase + s*2560 + t2;
      #pragma unroll
      for (int h=0;h<5;h++) acc += al[e][h]*bf2f(glp[h*256]);
    }
    g0p[qq][t2] = acc;
  }
  __syncthreads();
  if (t < 256){
    g0[t] = (g0p[0][t]+g0p[1][t]+g0p[2][t]+g0p[3][t])*0.2f + gbias[t];
  }
  __syncthreads();
  // hid gemm split-K: qq covers k in [qq*64, qq*64+64)
  {
    float acc = 0.f;
    int k0 = qq*64;
    for (int k=k0;k<k0+64;k++) acc += g0[k]*hidw[k*256+t2];
    hp[qq][t2] = acc;
  }
  __syncthreads();
  if (t < 256){
    hh[t] = fmaxf(hidb[t] + hp[0][t]+hp[1][t]+hp[2][t]+hp[3][t], 0.f);
  }
  __syncthreads();
  if (t < 8){
    float acc = advb[t];
    for (int k=0;k<256;k++) acc += hh[k]*advw[k*8+t];
    adv_s[t] = acc;
  } else if (t == 8){
    float acc = outb[0];
    for (int k=0;k<256;k++) acc += hh[k]*outw[k];
    v_s = acc;
  }
  __syncthreads();
  if (t < 8){
    float m = adv_s[0]+adv_s[1]+adv_s[2]+adv_s[3]+adv_s[4]+adv_s[5]+adv_s[6]+adv_s[7];
    out[b*8+t] = v_s + adv_s[t] - m*0.125f;
  }
}

extern "C" void kernel_launch(void* const* d_in, const int* in_sizes, int n_in,
                              void* d_out, int out_size, void* d_ws, size_t ws_size,
                              hipStream_t stream){
  const float* obs     = (const float*)d_in[0];
  const float* obs_map = (const float*)d_in[1];
  const int*   edges   = (const int*)d_in[2];
  const float* mlp_w = (const float*)d_in[4];
  const float* mlp_b = (const float*)d_in[5];
  const float* c1w = (const float*)d_in[6];  const float* c1b = (const float*)d_in[7];
  const float* c2w = (const float*)d_in[8];  const float* c2b = (const float*)d_in[9];
  const float* c3w = (const float*)d_in[10]; const float* c3b = (const float*)d_in[11];
  const float* fcw = (const float*)d_in[12]; const float* fcb = (const float*)d_in[13];
  const float* wih = (const float*)d_in[14]; const float* whh = (const float*)d_in[15];
  const float* bih = (const float*)d_in[16]; const float* bhh = (const float*)d_in[17];
  const float* gwl = (const float*)d_in[18]; const float* gbl = (const float*)d_in[19];
  const float* gwr = (const float*)d_in[20]; const float* gbr = (const float*)d_in[21];
  const float* gatt = (const float*)d_in[22]; const float* gbias = (const float*)d_in[23];
  const float* hidw = (const float*)d_in[24]; const float* hidb = (const float*)d_in[25];
  const float* outw = (const float*)d_in[26]; const float* outb = (const float*)d_in[27];
  const float* advw = (const float*)d_in[28]; const float* advb = (const float*)d_in[29];
  float* out = (float*)d_out;
  char* ws = (char*)d_ws;

  // workspace layout (c1o/c3o/fcpart aliased under glgr; consumed before glgr write)
  unsigned short* c1o  = (unsigned short*)(ws + 0);          // 6,553,600 B
  unsigned short* c3o  = (unsigned short*)(ws + 6553600);    // 1,605,632 B
  float*          fcpart = (float*)(ws + 16000000);          // 1,835,008 B
  unsigned short* glgr = (unsigned short*)(ws + 0);          // 32,768,000 B
  size_t o = 32768000;
  unsigned short* nemb    = (unsigned short*)(ws + o); o += 3276800;
  unsigned char*  wfrag8  = (unsigned char*)(ws + o);  o += 393216;
  unsigned short* mlpfrag = (unsigned short*)(ws + o); o += 16384;
  unsigned short* wlrT    = (unsigned short*)(ws + o); o += 1310720;
  unsigned short* fcwT    = (unsigned short*)(ws + o); o += 1605632;
  float* blbr             = (float*)(ws + o); o += 10240;
  unsigned short* c2wb    = (unsigned short*)(ws + o); o += 65536;
  unsigned short* c3wb    = (unsigned short*)(ws + o); o += 73728;

  prep_k<<<2206, 256, 0, stream>>>(wih, whh, gbl, gbr, mlp_w, c2w, c3w, fcw, gwl, gwr,
                                   wfrag8, mlpfrag, blbr, c2wb, c3wb, fcwT, wlrT);
  gruconv_k<<<448, 1024, 0, stream>>>(obs, wfrag8, mlpfrag, mlp_b, bih, bhh, nemb,
                                      obs_map, c1w, c1b, c1o);                    // gru + conv1
  conv23_k<<<256, 1024, 0, stream>>>(c1o, c2wb, c2b, c3wb, c3b, c3o);
  gemm_fc_k<<<112, 256, 0, stream>>>(c3o, fcwT, fcpart);                          // FC split-K
  fc_red_k<<<256, 256, 0, stream>>>(fcpart, fcb, nemb);                           // -> node 0
  gemm_k<<<4000, 256, 0, stream>>>(nemb, wlrT, blbr, glgr, 256, 2560, 1, 0, 40);  // gl|gr
  gat_k<<<256, 1024, 0, stream>>>(edges, glgr, gatt, gbias, hidw, hidb, outw, outb, advw, advb, out);
}

// Round 16
// 690.755 us; speedup vs baseline: 3.3582x; 1.0578x over previous
//
#include <hip/hip_runtime.h>
#include <cstdint>

typedef __attribute__((ext_vector_type(8))) __bf16 bf16x8;
typedef __attribute__((ext_vector_type(4))) float f32x4;
typedef __attribute__((ext_vector_type(4))) unsigned int uint4v;
typedef __attribute__((ext_vector_type(2))) unsigned int uint2v;
typedef __attribute__((ext_vector_type(4))) float float4v;
typedef __attribute__((ext_vector_type(2))) long long2v;

__device__ __forceinline__ unsigned short f2bf(float x){
  union { float f; unsigned u; } v; v.f = x;
  unsigned r = v.u + 0x7FFFu + ((v.u >> 16) & 1u);
  return (unsigned short)(r >> 16);
}
__device__ __forceinline__ float bf2f(unsigned short h){
  union { unsigned u; float f; } v; v.u = ((unsigned)h) << 16;
  return v.f;
}
__device__ __forceinline__ float bflo(unsigned u){
  union { unsigned x; float f; } v; v.x = u << 16; return v.f;
}
__device__ __forceinline__ float bfhi(unsigned u){
  union { unsigned x; float f; } v; v.x = u & 0xFFFF0000u; return v.f;
}
__device__ __forceinline__ f32x4 MFMA16(bf16x8 a, bf16x8 b, f32x4 c){
  return __builtin_amdgcn_mfma_f32_16x16x32_bf16(a, b, c, 0, 0, 0);
}
__device__ __forceinline__ f32x4 MFMA8(long a, long b, f32x4 c){
  return __builtin_amdgcn_mfma_f32_16x16x32_fp8_fp8(a, b, c, 0, 0, 0);
}
__device__ __forceinline__ unsigned char f2fp8(float x){
  int p = __builtin_amdgcn_cvt_pk_fp8_f32(x, x, 0, false);
  return (unsigned char)(p & 0xFF);
}

// ---------------- prep (merged: conversions + both LDS-tiled transposes) ----------
__global__ __launch_bounds__(256) void prep_k(
    const float* __restrict__ wih, const float* __restrict__ whh,
    const float* __restrict__ bl, const float* __restrict__ br,
    const float* __restrict__ mlpw,
    const float* __restrict__ c2w, const float* __restrict__ c3w,
    const float* __restrict__ fcw, const float* __restrict__ wl, const float* __restrict__ wr,
    unsigned char* __restrict__ wfrag8, unsigned short* __restrict__ mlpfrag,
    float* __restrict__ blbr,
    unsigned short* __restrict__ c2wb, unsigned short* __restrict__ c3wb,
    unsigned short* __restrict__ fcwT, unsigned short* __restrict__ wlrT){
  __shared__ float tile[64][65];
  int bid = blockIdx.x, t = threadIdx.x;
  if (bid < 1850){
    int i = bid*256 + t;
    if (i < 393216){
      int b16 = i & 15;
      int l   = (i >> 4) & 63;
      int chunk = i >> 10;           // (w*4+kkp)*6+mg
      int wkp = chunk / 6;
      int mg  = chunk - 6*wkp;
      int w = wkp >> 2, kkp = wkp & 3;
      int ks = b16 >> 3, e = b16 & 7;
      int kk = kkp*2 + ks;
      int mat = mg / 3, g = mg - 3*(mg/3);
      int n = g*256 + w*16 + (l & 15);
      int k = kk*32 + (l >> 4)*8 + e;
      float v = 16.f * (mat ? whh[n*256 + k] : wih[n*256 + k]);
      wfrag8[i] = f2fp8(v);
      return;
    }
    i -= 393216;
    if (i < 8192){
      int w = i >> 9;
      int r4 = i & 511;
      int l = r4 >> 3, e = r4 & 7;
      int n = w*16 + (l & 15);
      int k = (l >> 4)*8 + e;
      mlpfrag[i] = (k < 16) ? f2bf(mlpw[k*256 + n]) : (unsigned short)0;
      return;
    }
    i -= 8192;
    if (i < 2560){
      blbr[i] = (i < 1280) ? bl[i] : br[i-1280];
      return;
    }
    i -= 2560;
    if (i < 32768){ c2wb[i] = f2bf(c2w[i]); return; }
    i -= 32768;
    if (i < 36864){ c3wb[i] = f2bf(c3w[i]); }
    return;
  }
  if (bid < 2046){
    int tb = bid - 1850;
    int ti = tb >> 2, tj = tb & 3;
    for (int idx = t; idx < 4096; idx += 256){
      int r = idx >> 6, c = idx & 63;
      tile[r][c] = fcw[(size_t)(ti*64 + r)*256 + tj*64 + c];
    }
    __syncthreads();
    for (int idx = t; idx < 4096; idx += 256){
      int r = idx >> 6, c = idx & 63;
      fcwT[(size_t)(tj*64 + r)*3136 + ti*64 + c] = f2bf(tile[c][r]);
    }
    return;
  }
  {
    int tb = bid - 2046;
    int m = tb / 80; int rem = tb - m*80;
    int tk = rem / 20, tn = rem - tk*20;
    const float* src = m ? wr : wl;
    for (int idx = t; idx < 4096; idx += 256){
      int r = idx >> 6, c = idx & 63;
      tile[r][c] = src[(size_t)(tk*64 + r)*1280 + tn*64 + c];
    }
    __syncthreads();
    for (int idx = t; idx < 4096; idx += 256){
      int r = idx >> 6, c = idx & 63;
      wlrT[(size_t)(m*1280 + tn*64 + r)*256 + tk*64 + c] = f2bf(tile[c][r]);
    }
  }
}

// ---------------- conv23: fused conv2+conv3 per batch, LDS intermediates ----------
__global__ __launch_bounds__(1024) void conv23_k(const unsigned short* __restrict__ c1o,
              const unsigned short* __restrict__ c2wb, const float* __restrict__ c2b,
              const unsigned short* __restrict__ c3wb, const float* __restrict__ c3b,
              unsigned short* __restrict__ c3o){
  __shared__ __align__(16) char cs[102016];
  unsigned short* in_s = (unsigned short*)cs;            // [32][20][20] = 25600 B
  unsigned short* w2s  = (unsigned short*)(cs + 25600);  // 65536 B
  float* b2            = (float*)(cs + 91136);           // 256 B
  unsigned short* c2s  = (unsigned short*)(cs + 91392);  // [64][9][9] = 10368 B
  unsigned short* w3s  = (unsigned short*)cs;            // 73728 B (overlay, phase B)
  float* b3            = (float*)(cs + 101760);          // 256 B
  int b = blockIdx.x, t = threadIdx.x;
  int q = t >> 8, t2 = t & 255;
  for (int idx = t; idx < 12800; idx += 1024) in_s[idx] = c1o[(size_t)b*12800 + idx];
  for (int idx = t; idx < 32768; idx += 1024) w2s[idx] = c2wb[idx];
  if (t < 64) b2[t] = c2b[t];
  if (t >= 64 && t < 128) b3[t-64] = c3b[t-64];
  __syncthreads();
  for (int p = t2; p < 432; p += 256){
    int ocl = p / 27; int rem = p - ocl*27;
    int oy = rem / 3, og = rem - oy*3;
    int oc = q*16 + ocl;
    float a0=b2[oc],a1=b2[oc],a2=b2[oc];
    #pragma unroll 4
    for (int ic=0;ic<32;ic++){
      #pragma unroll
      for (int ky=0;ky<4;ky++){
        const unsigned short* row = &in_s[(ic*20 + oy*2+ky)*20 + og*6];
        float s[8];
        #pragma unroll
        for (int cc=0;cc<8;cc++) s[cc]=bf2f(row[cc]);
        const unsigned short* wp = &w2s[((oc*32+ic)*4+ky)*4];
        #pragma unroll
        for (int kx=0;kx<4;kx++){
          float wv = bf2f(wp[kx]);
          a0 += s[kx]*wv; a1 += s[2+kx]*wv; a2 += s[4+kx]*wv;
        }
      }
    }
    int ob = (oc*9 + oy)*9 + og*3;
    c2s[ob+0]=f2bf(fmaxf(a0,0.f)); c2s[ob+1]=f2bf(fmaxf(a1,0.f)); c2s[ob+2]=f2bf(fmaxf(a2,0.f));
  }
  __syncthreads();
  for (int idx = t; idx < 36864; idx += 1024) w3s[idx] = c3wb[idx];
  __syncthreads();
  for (int p = t2; p < 224; p += 256){
    int ocl = p / 14; int rem = p - ocl*14;
    int oy = rem >> 1, og = rem & 1;
    int ox0 = og*4; int nx = og ? 3 : 4;
    int oc = q*16 + ocl;
    float a[4]; a[0]=a[1]=a[2]=a[3]=b3[oc];
    for (int ic=0;ic<64;ic++){
      #pragma unroll
      for (int ky=0;ky<3;ky++){
        const unsigned short* row = &c2s[(ic*9 + oy+ky)*9 + ox0];
        float s[6];
        #pragma unroll
        for (int cc=0;cc<6;cc++) s[cc] = (ox0+cc < 9) ? bf2f(row[cc]) : 0.f;
        const unsigned short* wp = &w3s[((oc*64+ic)*3+ky)*3];
        #pragma unroll
        for (int kx=0;kx<3;kx++){
          float wv = bf2f(wp[kx]);
          #pragma unroll
          for (int jj=0;jj<4;jj++) a[jj] += s[jj+kx]*wv;
        }
      }
    }
    size_t ob = (size_t)b*3136 + oc*49 + oy*7 + ox0;
    #pragma unroll
    for (int jj=0;jj<4;jj++) if (jj < nx) c3o[ob+jj] = f2bf(fmaxf(a[jj],0.f));
  }
}

// ---------------- generic MFMA GEMM: C[m,n] = act(A[m,:]·B[n,:] + bias[n]) ----
__global__ __launch_bounds__(256) void gemm_k(const unsigned short* __restrict__ A,
              const unsigned short* __restrict__ B, const float* __restrict__ bias,
              unsigned short* __restrict__ C, int K, int ldc, int rowmul, int relu, int Nblk){
  __shared__ __align__(16) unsigned short As[64*32];
  __shared__ __align__(16) unsigned short Bs[64*32];
  int bid = blockIdx.x;
  int nb = bid % Nblk, mb = bid / Nblk;
  int t = threadIdx.x;
  int w = t >> 6, l = t & 63, lr = l & 15, lh = l >> 4;
  int sr = t >> 2, sq = t & 3;
  f32x4 acc[4];
  #pragma unroll
  for (int i=0;i<4;i++) acc[i] = (f32x4){0.f,0.f,0.f,0.f};
  int nkk = K >> 5;
  const size_t a_row = (size_t)(mb*64 + sr)*K;
  const size_t b_row = (size_t)(nb*64 + sr)*K;
  for (int kk=0;kk<nkk;kk++){
    uint4v av = *(const uint4v*)&A[a_row + kk*32 + sq*8];
    uint4v bv = *(const uint4v*)&B[b_row + kk*32 + sq*8];
    __syncthreads();
    *(uint4v*)((char*)As + ((sr*64 + sq*16) ^ ((sr&3)<<4))) = av;
    *(uint4v*)((char*)Bs + ((sr*64 + sq*16) ^ ((sr&3)<<4))) = bv;
    __syncthreads();
    int brow = w*16 + lr;
    bf16x8 bfr = *(const bf16x8*)((char*)Bs + ((brow*64 + lh*16) ^ ((brow&3)<<4)));
    #pragma unroll
    for (int mt=0;mt<4;mt++){
      int arow = mt*16 + lr;
      bf16x8 afr = *(const bf16x8*)((char*)As + ((arow*64 + lh*16) ^ ((arow&3)<<4)));
      acc[mt] = MFMA16(afr, bfr, acc[mt]);
    }
  }
  int col = nb*64 + w*16 + lr;
  float bn = bias[col];
  #pragma unroll
  for (int mt=0;mt<4;mt++){
    #pragma unroll
    for (int r=0;r<4;r++){
      int row = mb*64 + mt*16 + lh*4 + r;
      float v = acc[mt][r] + bn;
      if (relu) v = fmaxf(v, 0.f);
      C[(size_t)row*rowmul*ldc + col] = f2bf(v);
    }
  }
}

// ---------------- FC split-K GEMM: 112 blocks = 16 tiles x 7 K-slices, f32 partials ----
__global__ __launch_bounds__(256) void gemm_fc_k(const unsigned short* __restrict__ A,
              const unsigned short* __restrict__ B, float* __restrict__ P){
  __shared__ __align__(16) unsigned short As[64*32];
  __shared__ __align__(16) unsigned short Bs[64*32];
  int bid = blockIdx.x;
  int s = bid % 7, tile = bid / 7;
  int nb = tile & 3, mb = tile >> 2;
  int t = threadIdx.x;
  int w = t >> 6, l = t & 63, lr = l & 15, lh = l >> 4;
  int sr = t >> 2, sq = t & 3;
  f32x4 acc[4];
  #pragma unroll
  for (int i=0;i<4;i++) acc[i] = (f32x4){0.f,0.f,0.f,0.f};
  const int K = 3136;
  const size_t a_row = (size_t)(mb*64 + sr)*K;
  const size_t b_row = (size_t)(nb*64 + sr)*K;
  for (int kk = s*14; kk < s*14 + 14; kk++){
    uint4v av = *(const uint4v*)&A[a_row + kk*32 + sq*8];
    uint4v bv = *(const uint4v*)&B[b_row + kk*32 + sq*8];
    __syncthreads();
    *(uint4v*)((char*)As + ((sr*64 + sq*16) ^ ((sr&3)<<4))) = av;
    *(uint4v*)((char*)Bs + ((sr*64 + sq*16) ^ ((sr&3)<<4))) = bv;
    __syncthreads();
    int brow = w*16 + lr;
    bf16x8 bfr = *(const bf16x8*)((char*)Bs + ((brow*64 + lh*16) ^ ((brow&3)<<4)));
    #pragma unroll
    for (int mt=0;mt<4;mt++){
      int arow = mt*16 + lr;
      bf16x8 afr = *(const bf16x8*)((char*)As + ((arow*64 + lh*16) ^ ((arow&3)<<4)));
      acc[mt] = MFMA16(afr, bfr, acc[mt]);
    }
  }
  int col = nb*64 + w*16 + lr;
  #pragma unroll
  for (int mt=0;mt<4;mt++){
    #pragma unroll
    for (int r=0;r<4;r++){
      int row = mb*64 + mt*16 + lh*4 + r;
      P[(size_t)s*65536 + row*256 + col] = acc[mt][r];
    }
  }
}

// ---------------- FC reduce ----------------
__global__ __launch_bounds__(256) void fc_red_k(const float* __restrict__ P,
              const float* __restrict__ fcb, unsigned short* __restrict__ nemb){
  int idx = blockIdx.x*256 + threadIdx.x;       // 65536 total
  int row = idx >> 8, col = idx & 255;
  float sum = fcb[col];
  #pragma unroll
  for (int k=0;k<7;k++) sum += P[k*65536 + idx];
  nemb[(size_t)row*25*256 + col] = f2bf(fmaxf(sum, 0.f));
}

// ---------------- mega kernel: blocks 0..191 = GRU (1-barrier/step); 192..447 = conv1 ---
__global__ __launch_bounds__(1024, 4)
void gruconv_k(const float* __restrict__ obs,
              const unsigned char* __restrict__ wfrag8,
              const unsigned short* __restrict__ mlpfrag,
              const float* __restrict__ mlpb,
              const float* __restrict__ bih, const float* __restrict__ bhh,
              unsigned short* __restrict__ nemb,
              const float* __restrict__ cin, const float* __restrict__ c1w,
              const float* __restrict__ c1b, unsigned short* __restrict__ c1o){
  __shared__ __align__(16) char smem[121984];

  const int t = threadIdx.x, blk = blockIdx.x;

  if (blk >= 192){
    // ================= conv1 path (R11, unchanged) =================
    float* in_s = (float*)smem;                     // [4][3][24][84] = 96768 B
    float* w_s  = (float*)(smem + 96768);           // [32][3][8][8]  = 24576 B
    float* b_s  = (float*)(smem + 121344);          // [32]
    int b = blk - 192;
    int q = t >> 8, t2 = t & 255;
    float* inq = in_s + q*6048;
    for (int idx = t2; idx < 3*24*84; idx += 256){
      int ic = idx / (24*84); int rem = idx - ic*(24*84);
      int iy = rem / 84, ix = rem - iy*84;
      inq[idx] = cin[((size_t)(b*3+ic)*84 + (q*20 + iy))*84 + ix];
    }
    for (int idx = t; idx < 32*192; idx += 1024) w_s[idx] = c1w[idx];
    if (t < 32) b_s[t] = c1b[t];
    __syncthreads();
    for (int p = t2; p < 800; p += 256){
      int oc = p / 25; int rem = p - oc*25;
      int oy = rem / 5, og = rem - oy*5;
      float a0=b_s[oc],a1=b_s[oc],a2=b_s[oc],a3=b_s[oc];
      #pragma unroll
      for (int ic=0;ic<3;ic++){
        #pragma unroll
        for (int ky=0;ky<8;ky++){
          const float* row = &inq[(ic*24 + oy*4+ky)*84 + og*16];
          float s[20];
          #pragma unroll
          for (int cc=0;cc<20;cc++) s[cc]=row[cc];
          const float* wp = &w_s[(oc*3 + ic)*64 + ky*8];
          #pragma unroll
          for (int kx=0;kx<8;kx++){
            float wv = wp[kx];
            a0 += s[kx]*wv; a1 += s[4+kx]*wv; a2 += s[8+kx]*wv; a3 += s[12+kx]*wv;
          }
        }
      }
      size_t ob = ((size_t)(b*32+oc)*20 + (q*5+oy))*20 + og*4;
      c1o[ob+0]=f2bf(fmaxf(a0,0.f)); c1o[ob+1]=f2bf(fmaxf(a1,0.f));
      c1o[ob+2]=f2bf(fmaxf(a2,0.f)); c1o[ob+3]=f2bf(fmaxf(a3,0.f));
    }
    return;
  }

  // ================= GRU path (v11: full double-buffer, 1 barrier/step) ============
  unsigned short* obsA0 = (unsigned short*)smem;            // 2048 B each
  unsigned short* obsA1 = (unsigned short*)(smem + 2048);
  unsigned char* e8_0 = (unsigned char*)(smem + 4096);      // 8192 B each
  unsigned char* e8_1 = (unsigned char*)(smem + 12288);
  unsigned char* h8_0 = (unsigned char*)(smem + 20480);
  unsigned char* h8_1 = (unsigned char*)(smem + 28672);

  obsA0[t & 1023] = 0;   // zero k>=16 pad
  obsA1[t & 1023] = 0;
  for (int j = t; j < 8192; j += 1024) h8_0[j] = 0;

  const int w = t >> 6, l = t & 63, lr = l & 15, lh = l >> 4;
  const int jcol = w*16 + lr;
  const float bR  = bih[jcol]     + bhh[jcol];
  const float bZ  = bih[256+jcol] + bhh[256+jcol];
  const float bXN = bih[512+jcol];
  const float bHN = bhh[512+jcol];
  const float bMb = mlpb[jcol];
  const bf16x8 bMLP = *(const bf16x8*)(mlpfrag + w*512 + l*8);

  const unsigned char* wb8 = wfrag8 + w*24576 + l*16;

  const int srow = t >> 2, sk4 = t & 3;
  int rrS = blk*32 + srow; int bS = rrS/24, ndS = 1 + (rrS - bS*24);
  const float* obase4 = obs + (size_t)(bS*25 + ndS)*800 + sk4*4;
  const int obyte = (srow*64 + sk4*8) ^ ((srow&3)<<4);

  const int a8off = lr*256 + lh*8;
  const int xr8 = lr << 3;
  const int o16 = lh*16;
  const int oa0b = (lr*64 + o16) ^ ((lr&3)<<4);
  const int oa1b = ((16+lr)*64 + o16) ^ ((lr&3)<<4);
  const int hw0 = jcol;
  const float S = 1.f/256.f;

  f32x4 hs0 = (f32x4){0.f,0.f,0.f,0.f};
  f32x4 hs1 = (f32x4){0.f,0.f,0.f,0.f};

#define STAGE_OBS(DST, STEP) { \
  float4v ov = *(const float4v*)(obase4 + (size_t)(STEP)*16); \
  uint2v pk; \
  pk[0] = (unsigned)f2bf(ov[0]) | ((unsigned)f2bf(ov[1]) << 16); \
  pk[1] = (unsigned)f2bf(ov[2]) | ((unsigned)f2bf(ov[3]) << 16); \
  *(uint2v*)((char*)(DST) + obyte) = pk; }

#define EMB_COMPUTE(SRC, DST) { \
  f32x4 e0 = (f32x4){0.f,0.f,0.f,0.f}, e1 = (f32x4){0.f,0.f,0.f,0.f}; \
  bf16x8 oa0 = *(const bf16x8*)((char*)(SRC) + oa0b); \
  bf16x8 oa1 = *(const bf16x8*)((char*)(SRC) + oa1b); \
  e0 = MFMA16(oa0, bMLP, e0); \
  e1 = MFMA16(oa1, bMLP, e1); \
  _Pragma("unroll") \
  for (int r=0;r<4;r++){ \
    int m = lh*4 + r; \
    (DST)[(m*256 + hw0) ^ ((m&15)<<3)] = f2fp8(fmaxf(e0[r] + bMb, 0.f)*16.f); \
    int m2 = m + 16; \
    (DST)[(m2*256 + hw0) ^ ((m2&15)<<3)] = f2fp8(fmaxf(e1[r] + bMb, 0.f)*16.f); \
  } }

  // ---- prologue: obs(0)->obsA0, obs(1)->obsA1, emb(0)->e8_0, h8_0 = 0 ----
  __syncthreads();
  if (t < 128){
    STAGE_OBS(obsA0, 0)
    STAGE_OBS(obsA1, 1)
  }
  __syncthreads();
  EMB_COMPUTE(obsA0, e8_0)
  __syncthreads();

  for (int step=0; step<50; step++){
    const int c = step & 1;
    const unsigned char* ebuf = c ? e8_1 : e8_0;
    const unsigned char* hbuf = c ? h8_1 : h8_0;
    unsigned char* enew = c ? e8_0 : e8_1;
    unsigned char* hnewb = c ? h8_0 : h8_1;
    const unsigned short* obsRd = c ? obsA0 : obsA1;   // holds obs(step+1)
    unsigned short* obsWr = c ? obsA1 : obsA0;         // dead slot -> obs(step+2)
    const bool stg = (t < 128) && (step < 48);
    // ---- issue obs(t+2) loads, fp8 GEMM(t) from [c] buffers, write obsA[c-slot] ----
    float4v ov;
    if (stg) ov = *(const float4v*)(obase4 + (size_t)(step+2)*16);

    f32x4 aR0=(f32x4){0,0,0,0}, aR1=(f32x4){0,0,0,0};
    f32x4 aZ0=(f32x4){0,0,0,0}, aZ1=(f32x4){0,0,0,0};
    f32x4 aN0=(f32x4){0,0,0,0}, aN1=(f32x4){0,0,0,0};
    f32x4 aM0=(f32x4){0,0,0,0}, aM1=(f32x4){0,0,0,0};
    __builtin_amdgcn_s_setprio(1);
    #pragma unroll 2
    for (int kkp=0;kkp<4;kkp++){
      const unsigned char* wk8 = wb8 + kkp*6144;
      long2v wIR = *(const long2v*)(wk8);
      long2v wIZ = *(const long2v*)(wk8 + 1024);
      long2v wIN = *(const long2v*)(wk8 + 2048);
      long2v wHR = *(const long2v*)(wk8 + 3072);
      long2v wHZ = *(const long2v*)(wk8 + 4096);
      long2v wHN = *(const long2v*)(wk8 + 5120);
      {
        int kk = kkp*2;
        int ab = a8off + kk*32;
        long eA0 = *(const long*)(ebuf + (ab ^ xr8));
        long eA1 = *(const long*)(ebuf + ((ab + 4096) ^ xr8));
        long hA0 = *(const long*)(hbuf + (ab ^ xr8));
        long hA1 = *(const long*)(hbuf + ((ab + 4096) ^ xr8));
        aR0 = MFMA8(eA0, wIR[0], aR0);  aR0 = MFMA8(hA0, wHR[0], aR0);
        aR1 = MFMA8(eA1, wIR[0], aR1);  aR1 = MFMA8(hA1, wHR[0], aR1);
        aZ0 = MFMA8(eA0, wIZ[0], aZ0);  aZ0 = MFMA8(hA0, wHZ[0], aZ0);
        aZ1 = MFMA8(eA1, wIZ[0], aZ1);  aZ1 = MFMA8(hA1, wHZ[0], aZ1);
        aN0 = MFMA8(eA0, wIN[0], aN0);  aN1 = MFMA8(eA1, wIN[0], aN1);
        aM0 = MFMA8(hA0, wHN[0], aM0);  aM1 = MFMA8(hA1, wHN[0], aM1);
      }
      {
        int kk = kkp*2 + 1;
        int ab = a8off + kk*32;
        long eA0 = *(const long*)(ebuf + (ab ^ xr8));
        long eA1 = *(const long*)(ebuf + ((ab + 4096) ^ xr8));
        long hA0 = *(const long*)(hbuf + (ab ^ xr8));
        long hA1 = *(const long*)(hbuf + ((ab + 4096) ^ xr8));
        aR0 = MFMA8(eA0, wIR[1], aR0);  aR0 = MFMA8(hA0, wHR[1], aR0);
        aR1 = MFMA8(eA1, wIR[1], aR1);  aR1 = MFMA8(hA1, wHR[1], aR1);
        aZ0 = MFMA8(eA0, wIZ[1], aZ0);  aZ0 = MFMA8(hA0, wHZ[1], aZ0);
        aZ1 = MFMA8(eA1, wIZ[1], aZ1);  aZ1 = MFMA8(hA1, wHZ[1], aZ1);
        aN0 = MFMA8(eA0, wIN[1], aN0);  aN1 = MFMA8(eA1, wIN[1], aN1);
        aM0 = MFMA8(hA0, wHN[1], aM0);  aM1 = MFMA8(hA1, wHN[1], aM1);
      }
    }
    __builtin_amdgcn_s_setprio(0);
    if (stg){
      uint2v pk;
      pk[0] = (unsigned)f2bf(ov[0]) | ((unsigned)f2bf(ov[1]) << 16);
      pk[1] = (unsigned)f2bf(ov[2]) | ((unsigned)f2bf(ov[3]) << 16);
      *(uint2v*)((char*)obsWr + obyte) = pk;
    }
    // ---- emb(t+1) from obsA[n] -> e8[n]  (no barrier needed: disjoint buffers) ----
    if (step < 49){
      EMB_COMPUTE(obsRd, enew)
    }
    // ---- gate update -> h8[n] ----
    #pragma unroll
    for (int mt=0;mt<2;mt++){
      f32x4 vR = mt ? aR1 : aR0;
      f32x4 vZ = mt ? aZ1 : aZ0;
      f32x4 vN = mt ? aN1 : aN0;
      f32x4 vM = mt ? aM1 : aM0;
      #pragma unroll
      for (int r=0;r<4;r++){
        float rp = vR[r]*S + bR;
        float zp = vZ[r]*S + bZ;
        float xn = vN[r]*S + bXN;
        float hn = vM[r]*S + bHN;
        float rg = 1.f/(1.f + __expf(-rp));
        float zg = 1.f/(1.f + __expf(-zp));
        float arg = xn + rg*hn;
        float e2 = __expf(2.f*arg);
        float nv = (e2 - 1.f)/(e2 + 1.f);
        float hold = mt ? hs1[r] : hs0[r];
        float hnew = (1.f - zg)*nv + zg*hold;
        if (mt) hs1[r] = hnew; else hs0[r] = hnew;
        int m = mt*16 + lh*4 + r;
        hnewb[(m*256 + hw0) ^ ((m&15)<<3)] = f2fp8(hnew*16.f);
        if (step == 49){
          int rr = blk*32 + m; int b = rr/24; int nd = 1 + (rr - b*24);
          nemb[(size_t)(b*25+nd)*256 + jcol] = f2bf(hnew);
        }
      }
    }
    __syncthreads();   // all [n]-buffer writes + obsA write visible for next step
  }
#undef STAGE_OBS
#undef EMB_COMPUTE
}

// ---------------- GAT v2: 1024 threads/graph ----------------
__global__ __launch_bounds__(1024) void gat_k(const int* __restrict__ edges,
              const unsigned short* __restrict__ glgr,
              const float* __restrict__ att, const float* __restrict__ gbias,
              const float* __restrict__ hidw, const float* __restrict__ hidb,
              const float* __restrict__ outw, const float* __restrict__ outb,
              const float* __restrict__ advw, const float* __restrict__ advb,
              float* __restrict__ out){
  __shared__ int src_s[125], dst_s[125];
  __shared__ __align__(16) float att_s[1280];
  __shared__ float sc[125][5], al[125][5];
  __shared__ float mx[25][5], dn[25][5];
  __shared__ float g0p[4][256];
  __shared__ float hp[4][256];
  __shared__ float g0[256], hh[256];
  __shared__ float adv_s[8], v_s;
  __shared__ int e0[125]; __shared__ int ne0;

  int b = blockIdx.x, t = threadIdx.x;
  int qq = t >> 8, t2 = t & 255;
  if (t < 100){ src_s[t] = edges[b*200 + t]; dst_s[t] = edges[b*200 + 100 + t]; }
  else if (t < 125){ src_s[t] = t - 100; dst_s[t] = t - 100; }
  for (int j = t; j < 1280; j += 1024) att_s[j] = att[j];
  __syncthreads();
  if (t == 0){ int c = 0; for (int e=0;e<125;e++) if (dst_s[e]==0) e0[c++]=e; ne0 = c; }
  const unsigned short* gbase = glgr + (size_t)b*25*2560;
  if (t < 625){
    int e = t/5, h = t - 5*(t/5);
    const unsigned short* glp = gbase + src_s[e]*2560 + h*256;
    const unsigned short* grp = gbase + dst_s[e]*2560 + 1280 + h*256;
    const float* ap = &att_s[h*256];
    float acc = 0.f;
    #pragma unroll 4
    for (int c=0;c<256;c+=8){
      uint4v gu = *(const uint4v*)&glp[c];
      uint4v ru = *(const uint4v*)&grp[c];
      #pragma unroll
      for (int q=0;q<4;q++){
        float s0 = bflo(gu[q]) + bflo(ru[q]);
        float s1 = bfhi(gu[q]) + bfhi(ru[q]);
        s0 = (s0 > 0.f) ? s0 : 0.2f*s0;
        s1 = (s1 > 0.f) ? s1 : 0.2f*s1;
        acc += s0*ap[c+2*q] + s1*ap[c+2*q+1];
      }
    }
    sc[e][h] = acc;
  }
  __syncthreads();
  if (t < 125){
    int j = t/5, h = t - 5*(t/5);
    float m = -1e30f;
    for (int e=0;e<125;e++) if (dst_s[e]==j) m = fmaxf(m, sc[e][h]);
    float d = 0.f;
    for (int e=0;e<125;e++) if (dst_s[e]==j) d += __expf(sc[e][h]-m);
    mx[j][h] = m; dn[j][h] = d;
  }
  __syncthreads();
  if (t < 625){
    int e = t/5, h = t - 5*(t/5);
    int dd = dst_s[e];
    al[e][h] = __expf(sc[e][h] - mx[dd][h]) / dn[dd][h];
  }
  __syncthreads();
  if (t < 101){
    out[2048 + b*101 + t] = (al[t][0]+al[t][1]+al[t][2]+al[t][3]+al[t][4])*0.2f;
  }
  {
    float acc = 0.f;
    for (int x=qq; x<ne0; x+=4){
      int e = e0[x]; int s = src_s[e];
      const unsigned short* glp = gbase + s*2560 + t2;
      #pragma unroll
      for (int h=0;h<5;h++) acc += al[e][h]*bf2f(glp[h*256]);
    }
    g0p[qq][t2] = acc;
  }
  __syncthreads();
  if (t < 256){
    g0[t] = (g0p[0][t]+g0p[1][t]+g0p[2][t]+g0p[3][t])*0.2f + gbias[t];
  }
  __syncthreads();
  {
    float acc = 0.f;
    int k0 = qq*64;
    for (int k=k0;k<k0+64;k++) acc += g0[k]*hidw[k*256+t2];
    hp[qq][t2] = acc;
  }
  __syncthreads();
  if (t < 256){
    hh[t] = fmaxf(hidb[t] + hp[0][t]+hp[1][t]+hp[2][t]+hp[3][t], 0.f);
  }
  __syncthreads();
  if (t < 8){
    float acc = advb[t];
    for (int k=0;k<256;k++) acc += hh[k]*advw[k*8+t];
    adv_s[t] = acc;
  } else if (t == 8){
    float acc = outb[0];
    for (int k=0;k<256;k++) acc += hh[k]*outw[k];
    v_s = acc;
  }
  __syncthreads();
  if (t < 8){
    float m = adv_s[0]+adv_s[1]+adv_s[2]+adv_s[3]+adv_s[4]+adv_s[5]+adv_s[6]+adv_s[7];
    out[b*8+t] = v_s + adv_s[t] - m*0.125f;
  }
}

extern "C" void kernel_launch(void* const* d_in, const int* in_sizes, int n_in,
                              void* d_out, int out_size, void* d_ws, size_t ws_size,
                              hipStream_t stream){
  const float* obs     = (const float*)d_in[0];
  const float* obs_map = (const float*)d_in[1];
  const int*   edges   = (const int*)d_in[2];
  const float* mlp_w = (const float*)d_in[4];
  const float* mlp_b = (const float*)d_in[5];
  const float* c1w = (const float*)d_in[6];  const float* c1b = (const float*)d_in[7];
  const float* c2w = (const float*)d_in[8];  const float* c2b = (const float*)d_in[9];
  const float* c3w = (const float*)d_in[10]; const float* c3b = (const float*)d_in[11];
  const float* fcw = (const float*)d_in[12]; const float* fcb = (const float*)d_in[13];
  const float* wih = (const float*)d_in[14]; const float* whh = (const float*)d_in[15];
  const float* bih = (const float*)d_in[16]; const float* bhh = (const float*)d_in[17];
  const float* gwl = (const float*)d_in[18]; const float* gbl = (const float*)d_in[19];
  const float* gwr = (const float*)d_in[20]; const float* gbr = (const float*)d_in[21];
  const float* gatt = (const float*)d_in[22]; const float* gbias = (const float*)d_in[23];
  const float* hidw = (const float*)d_in[24]; const float* hidb = (const float*)d_in[25];
  const float* outw = (const float*)d_in[26]; const float* outb = (const float*)d_in[27];
  const float* advw = (const float*)d_in[28]; const float* advb = (const float*)d_in[29];
  float* out = (float*)d_out;
  char* ws = (char*)d_ws;

  // workspace layout (c1o/c3o/fcpart aliased under glgr; consumed before glgr write)
  unsigned short* c1o  = (unsigned short*)(ws + 0);          // 6,553,600 B
  unsigned short* c3o  = (unsigned short*)(ws + 6553600);    // 1,605,632 B
  float*          fcpart = (float*)(ws + 16000000);          // 1,835,008 B
  unsigned short* glgr = (unsigned short*)(ws + 0);          // 32,768,000 B
  size_t o = 32768000;
  unsigned short* nemb    = (unsigned short*)(ws + o); o += 3276800;
  unsigned char*  wfrag8  = (unsigned char*)(ws + o);  o += 393216;
  unsigned short* mlpfrag = (unsigned short*)(ws + o); o += 16384;
  unsigned short* wlrT    = (unsigned short*)(ws + o); o += 1310720;
  unsigned short* fcwT    = (unsigned short*)(ws + o); o += 1605632;
  float* blbr             = (float*)(ws + o); o += 10240;
  unsigned short* c2wb    = (unsigned short*)(ws + o); o += 65536;
  unsigned short* c3wb    = (unsigned short*)(ws + o); o += 73728;

  prep_k<<<2206, 256, 0, stream>>>(wih, whh, gbl, gbr, mlp_w, c2w, c3w, fcw, gwl, gwr,
                                   wfrag8, mlpfrag, blbr, c2wb, c3wb, fcwT, wlrT);
  gruconv_k<<<448, 1024, 0, stream>>>(obs, wfrag8, mlpfrag, mlp_b, bih, bhh, nemb,
                                      obs_map, c1w, c1b, c1o);                    // gru + conv1
  conv23_k<<<256, 1024, 0, stream>>>(c1o, c2wb, c2b, c3wb, c3b, c3o);
  gemm_fc_k<<<112, 256, 0, stream>>>(c3o, fcwT, fcpart);                          // FC split-K
  fc_red_k<<<256, 256, 0, stream>>>(fcpart, fcb, nemb);                           // -> node 0
  gemm_k<<<4000, 256, 0, stream>>>(nemb, wlrT, blbr, glgr, 256, 2560, 1, 0, 40);  // gl|gr
  gat_k<<<256, 1024, 0, stream>>>(edges, glgr, gatt, gbias, hidw, hidb, outw, outb, advw, advb, out);
}